// Round 3
// baseline (293.783 us; speedup 1.0000x reference)
//
#include <hip/hip_runtime.h>
#include <hip/hip_bf16.h>
#include <stdint.h>

// Problem constants (fixed by reference setup_inputs)
#define T_TOKENS 32768     // 32*1024
#define D_IN     768
#define D_OUT    256
#define N_EXP    8
#define S_TOT    (T_TOKENS*2)   // 65536 routed slots
#define S_PAD    66560          // 65536 + 8*128 worst-case per-expert 128-padding
#define KSPLIT   6              // gate k-split: 768 = 6 x 128
#define NKB      24             // K-blocks of 32 in d_in

typedef __attribute__((ext_vector_type(8))) short bf16x8;
typedef __attribute__((ext_vector_type(4))) float f32x4;

__device__ __forceinline__ unsigned short f2bf(float f) {
    unsigned u = __float_as_uint(f);
    return (unsigned short)((u + 0x7FFFu + ((u >> 16) & 1u)) >> 16);  // RNE
}
__device__ __forceinline__ unsigned pack_bf2(float a, float b) {
    return (unsigned)f2bf(a) | ((unsigned)f2bf(b) << 16);
}

// async global->LDS, 16B per lane. LDS dest must be wave-uniform base + lane*16.
__device__ __forceinline__ void async16(void* lds, const void* g) {
    __builtin_amdgcn_global_load_lds(
        (const __attribute__((address_space(1))) unsigned int*)g,
        (__attribute__((address_space(3))) unsigned int*)lds, 16, 0, 0);
}

// ---- W fp32 [e][k][n] -> bf16 k-blocked [e][kb][n][32kk]; zeroes counts+cursors ----
// Each (e,kb) tile is a contiguous 16 KB slab -> GEMM B staging is fully coalesced.
__global__ __launch_bounds__(256) void convw_kernel(
        const float* __restrict__ W, unsigned short* __restrict__ WTb,
        int* __restrict__ zero16) {
    if (blockIdx.x == 0 && threadIdx.x < 16) zero16[threadIdx.x] = 0;  // counts+cursors
    int eb_ = blockIdx.x;                            // e*NKB + kb, 0..191
    int n = threadIdx.x;
    const float* src = W + ((size_t)(eb_ / NKB) * D_IN + (eb_ % NKB) * 32) * 256 + n;
    unsigned pk[16];
    #pragma unroll
    for (int j = 0; j < 16; j++)                     // reads coalesced (n fastest)
        pk[j] = pack_bf2(src[(2*j) * 256], src[(2*j+1) * 256]);
    unsigned* dst = (unsigned*)(WTb + ((size_t)eb_ * 256 + n) * 32);  // 64 B/thread contig
    #pragma unroll
    for (int j = 0; j < 16; j++) dst[j] = pk[j];
}

// ---- gate stage 1: k-split partial logits. grid=(512,KSPLIT): 64 tokens x 128 k each.
__global__ __launch_bounds__(64) void gate_partial_kernel(
        const float* __restrict__ x, const float* __restrict__ gW,
        unsigned short* __restrict__ xbf, float* __restrict__ partial) {
    __shared__ float tile[64 * 65];
    int tid = threadIdx.x;
    int t0  = blockIdx.x * 64;
    int kq  = blockIdx.y;                            // k-slice 0..KSPLIT-1
    int c16 = tid & 15, rb = tid >> 4;
    float acc[8] = {0,0,0,0,0,0,0,0};
    #pragma unroll 1
    for (int j = 0; j < 2; j++) {
        int kc = kq * 128 + j * 64;
        #pragma unroll
        for (int i = 0; i < 16; i++) {
            int row = i * 4 + rb;
            size_t g = (size_t)(t0 + row) * D_IN + kc + c16 * 4;
            float4 v = *(const float4*)(x + g);
            uint2 p; p.x = pack_bf2(v.x, v.y); p.y = pack_bf2(v.z, v.w);
            *(uint2*)(xbf + g) = p;                  // fused bf16 emit (coalesced 8B)
            float* d = &tile[row * 65 + c16 * 4];
            d[0] = v.x; d[1] = v.y; d[2] = v.z; d[3] = v.w;  // ~2-way banks: free
        }
        __syncthreads();
        const float* gr = gW + (size_t)kc * 8;       // wave-uniform -> s_load
        #pragma unroll 8
        for (int kk = 0; kk < 64; kk++) {
            float xv = tile[tid * 65 + kk];          // bank (l+kk)%32: conflict-free
            #pragma unroll
            for (int e = 0; e < 8; e++) acc[e] += xv * gr[kk * 8 + e];
        }
        __syncthreads();
    }
    float* dst = partial + ((size_t)kq * T_TOKENS + t0 + tid) * 8;
    float4 o0 = {acc[0], acc[1], acc[2], acc[3]};
    float4 o1 = {acc[4], acc[5], acc[6], acc[7]};
    *(float4*)dst = o0; *(float4*)(dst + 4) = o1;    // 32B/token, coalesced
}

// ---- gate stage 2: sum partials (FIXED order: deterministic), softmax, top-2, hist ----
__global__ __launch_bounds__(256) void gate_final_kernel(
        const float* __restrict__ partial, const float* __restrict__ gb,
        float* __restrict__ topk_w, int* __restrict__ topk_e, int* __restrict__ counts) {
    __shared__ int h[8];
    int tid = threadIdx.x;
    if (tid < 8) h[tid] = 0;
    __syncthreads();
    int t = blockIdx.x * 256 + tid;
    float acc[8] = {0,0,0,0,0,0,0,0};
    #pragma unroll
    for (int q = 0; q < KSPLIT; q++) {               // fixed summation order
        const float* p = partial + ((size_t)q * T_TOKENS + t) * 8;
        float4 a = *(const float4*)p;
        float4 b = *(const float4*)(p + 4);
        acc[0] += a.x; acc[1] += a.y; acc[2] += a.z; acc[3] += a.w;
        acc[4] += b.x; acc[5] += b.y; acc[6] += b.z; acc[7] += b.w;
    }
    float mx = -1e30f;
    #pragma unroll
    for (int e = 0; e < 8; e++) { acc[e] += gb[e]; mx = fmaxf(mx, acc[e]); }
    float w[8], s = 0.f;
    #pragma unroll
    for (int e = 0; e < 8; e++) { w[e] = expf(acc[e] - mx); s += w[e]; }
    float inv = 1.0f / s;
    int e0 = 0; float b0 = -1.f;
    #pragma unroll
    for (int e = 0; e < 8; e++) if (w[e] > b0) { b0 = w[e]; e0 = e; }   // ties -> lowest idx
    int e1 = 0; float b1 = -1.f;
    #pragma unroll
    for (int e = 0; e < 8; e++) if (e != e0 && w[e] > b1) { b1 = w[e]; e1 = e; }
    topk_w[t*2]   = b0 * inv;
    topk_w[t*2+1] = b1 * inv;
    topk_e[t*2]   = e0;
    topk_e[t*2+1] = e1;
    atomicAdd(&h[e0], 1); atomicAdd(&h[e1], 1);
    __syncthreads();
    if (tid < 8) atomicAdd(&counts[tid], h[tid]);
}

// ---- scatter (token,w) into expert buckets; 128-aligned regions ----
// Block 0 additionally zeroes slot_w over the interior pad gaps (<=127 per expert),
// replacing the 0.5 MB slot memset. slot_token pads stay garbage (GEMM clamps; their
// outputs are discarded because slot_w==0).
__global__ void scatter_kernel(const int* __restrict__ topk_e, const float* __restrict__ topk_w,
                               const int* __restrict__ counts, int* __restrict__ cursors,
                               int* __restrict__ slot_token, float* __restrict__ slot_w) {
    int offs[9]; offs[0] = 0;
    #pragma unroll
    for (int e = 0; e < 8; e++) offs[e+1] = offs[e] + ((counts[e] + 127) & ~127);
    if (blockIdx.x == 0) {                           // zero pad-gap weights
        #pragma unroll
        for (int e = 0; e < 8; e++) {
            int start = offs[e] + counts[e];
            for (int i = start + threadIdx.x; i < offs[e+1]; i += 256) slot_w[i] = 0.f;
        }
    }
    __shared__ int hcnt[8], hbase[8];
    if (threadIdx.x < 8) hcnt[threadIdx.x] = 0;
    __syncthreads();
    int idx[4], ee[4], lr[4];
    int base = blockIdx.x * 256 * 4 + threadIdx.x;
    #pragma unroll
    for (int j = 0; j < 4; j++) {
        idx[j] = base + j * 256;
        ee[j]  = topk_e[idx[j]];
        lr[j]  = atomicAdd(&hcnt[ee[j]], 1);
    }
    __syncthreads();
    if (threadIdx.x < 8) hbase[threadIdx.x] = atomicAdd(&cursors[threadIdx.x], hcnt[threadIdx.x]);
    __syncthreads();
    #pragma unroll
    for (int j = 0; j < 4; j++) {
        int slot = offs[ee[j]] + hbase[ee[j]] + lr[j];
        slot_token[slot] = idx[j] >> 1;
        slot_w[slot]     = topk_w[idx[j]];
    }
}

// ---- routed GEMM, R8: back to R1 geometry (128x256 tile, 512 thr / 8 waves 2Mx4N,
// BK=32, 3-stage counted-vmcnt pipeline, 72 KB LDS -> 2 blocks/CU) which keeps the
// A-gather staged EXACTLY ONCE per slot (R2's column-split doubled A traffic: the
// measured ~4 TB/s staging ceiling made that +27 us). Epilogue is the fused weighted
// combine via device atomicAdd (removes the 68 MB routed write + 132 MB combine
// round-trip + a kernel launch). Pads have slot_w==0 -> predicated off.
__global__ __launch_bounds__(512, 2) void moe_gemm_kernel(
        const unsigned short* __restrict__ xbf, const unsigned short* __restrict__ WTb,
        const float* __restrict__ eb, const int* __restrict__ counts,
        const int* __restrict__ slot_token, const float* __restrict__ slot_w,
        float* __restrict__ out) {
    __shared__ unsigned short A_lds[3][128 * 32];    // 3 x 8 KB
    __shared__ unsigned short B_lds[3][256 * 32];    // 3 x 16 KB  -> 72 KB total

    // bijective XCD-chunked swizzle: 520 = 8 * 65; consecutive lbid share B panel
    int lbid = (blockIdx.x & 7) * ((int)gridDim.x >> 3) + (blockIdx.x >> 3);

    int offs[9]; offs[0] = 0;
    #pragma unroll
    for (int e = 0; e < 8; e++) offs[e+1] = offs[e] + ((counts[e] + 127) & ~127);
    int row0 = lbid * 128;
    if (row0 >= offs[8]) return;                     // uniform exit (pad tiles)
    int expert = 0;
    #pragma unroll
    for (int e = 0; e < 8; e++) if (row0 >= offs[e]) expert = e;

    int tid  = threadIdx.x;
    int wave = tid >> 6, lane = tid & 63;
    int lrow = lane & 15, lquad = lane >> 4;
    int wm = wave >> 2, wn = wave & 3;               // 2 (M) x 4 (N) wave grid

    // ---- staging sources (LDS dest linear-by-thread; chunk-rotate the SOURCE) ----
    // A: 512 16B-chunks (128 rows x 4) = 1 chunk/thread; gathered rows (row-major xbf)
    int ar = tid >> 2, ap = tid & 3;
    int alc = (ap - (ar >> 1)) & 3;                  // logical chunk at this phys slot
    int tok = slot_token[row0 + ar];
    tok = (tok < 0 || tok >= T_TOKENS) ? 0 : tok;    // pad slots hold garbage: clamp
    const unsigned short* asrc = xbf + (size_t)tok * D_IN + alc * 8;

    // B: k-blocked tile = contiguous 16 KB; 2 chunks/thread, offset within tile fixed
    const unsigned short* bexp = WTb + (size_t)expert * NKB * 8192;
    int boff[2];
    #pragma unroll
    for (int i = 0; i < 2; i++) {
        int c = i * 512 + tid;
        int r = c >> 2, p = c & 3;
        int lc = (p - (r >> 1)) & 3;
        boff[i] = r * 32 + lc * 8;                   // shorts within 16 KB tile
    }

    // frag LDS offsets (shorts), constant across K
    int a_off[4], b_off[4];
    #pragma unroll
    for (int m = 0; m < 4; m++) {
        int r = wm * 64 + m * 16 + lrow;
        a_off[m] = r * 32 + ((lquad + (r >> 1)) & 3) * 8;
    }
    #pragma unroll
    for (int q = 0; q < 4; q++) {
        int r = wn * 64 + q * 16 + lrow;
        b_off[q] = r * 32 + ((lquad + (r >> 1)) & 3) * 8;
    }

    f32x4 acc[4][4];
    #pragma unroll
    for (int m = 0; m < 4; m++)
        #pragma unroll
        for (int q = 0; q < 4; q++) acc[m][q] = (f32x4){0,0,0,0};

    auto stage = [&](int kb, int st) {               // 3 VMEM instrs per thread
        async16(&A_lds[st][tid * 8], asrc + kb * 32);
        const unsigned short* tb = bexp + (size_t)kb * 8192;
        #pragma unroll
        for (int i = 0; i < 2; i++)
            async16(&B_lds[st][(i * 512 + tid) * 8], tb + boff[i]);
    };

    stage(0, 0);
    stage(1, 1);
    for (int s = 0; s < NKB; s++) {
        // wait: oldest in-flight stage (s) done; stage(s+1)'s 3 loads stay in flight
        if (s == NKB - 1) asm volatile("s_waitcnt vmcnt(0)" ::: "memory");
        else              asm volatile("s_waitcnt vmcnt(3)" ::: "memory");
        asm volatile("s_barrier" ::: "memory");      // raw: no compiler vmcnt(0) drain
        if (s + 2 < NKB) stage(s + 2, (s + 2) % 3);
        int p = s % 3;
        bf16x8 a[4], b[4];
        #pragma unroll
        for (int m = 0; m < 4; m++) a[m] = *(const bf16x8*)&A_lds[p][a_off[m]];
        #pragma unroll
        for (int q = 0; q < 4; q++) b[q] = *(const bf16x8*)&B_lds[p][b_off[q]];
        __builtin_amdgcn_s_setprio(1);
        #pragma unroll
        for (int q = 0; q < 4; q++)
            #pragma unroll
            for (int m = 0; m < 4; m++)
                acc[m][q] = __builtin_amdgcn_mfma_f32_16x16x32_bf16(a[m], b[q], acc[m][q], 0, 0, 0);
        __builtin_amdgcn_s_setprio(0);
    }

    // fused combine epilogue: D mapping col=lane&15, row=quad*4+reg
    float bias_q[4];
    #pragma unroll
    for (int q = 0; q < 4; q++)
        bias_q[q] = eb[expert * D_OUT + wn * 64 + q * 16 + lrow];
    #pragma unroll
    for (int m = 0; m < 4; m++) {
        #pragma unroll
        for (int r = 0; r < 4; r++) {
            int slot = row0 + wm * 64 + m * 16 + lquad * 4 + r;
            int tk   = slot_token[slot];
            float wgt = slot_w[slot];                // pads: wgt==0 (scatter zeroed)
            if (wgt != 0.f) {
                float* drow = out + (size_t)tk * D_OUT + wn * 64;
                #pragma unroll
                for (int q = 0; q < 4; q++)
                    atomicAdd(drow + q * 16 + lrow, wgt * (acc[m][q][r] + bias_q[q]));
            }
        }
    }
}

extern "C" void kernel_launch(void* const* d_in, const int* in_sizes, int n_in,
                              void* d_out, int out_size, void* d_ws, size_t ws_size,
                              hipStream_t stream) {
    const float* x  = (const float*)d_in[0];
    const float* gW = (const float*)d_in[1];
    const float* gb = (const float*)d_in[2];
    const float* eW = (const float*)d_in[3];
    const float* eb = (const float*)d_in[4];
    float* out = (float*)d_out;
    char* ws = (char*)d_ws;

    // ws layout
    float* topk_w      = (float*)(ws + 0);                 // 256 KB
    int*   topk_e      = (int*)  (ws + 262144);            // 256 KB
    int*   counts      = (int*)  (ws + 524288);            // 8 ints
    int*   cursors     = (int*)  (ws + 524320);            // 8 ints  (contiguous w/ counts)
    int*   slot_token  = (int*)  (ws + 524416);            // 266240 B (S_PAD)
    float* slot_w      = (float*)(ws + 790656);            // 266240 B (S_PAD)
    float* partial     = (float*)(ws + 1319040);           // 6 MB  [KSPLIT][T][8] fp32
    unsigned short* WTb= (unsigned short*)(ws + 7610496);  // 3 MB bf16 W k-blocked
    unsigned short* xbf= (unsigned short*)(ws + 10756224); // 48 MB bf16 x

    // out must be zero before the gemm's atomic combine; issued first (stream order).
    hipMemsetAsync(out, 0, (size_t)out_size * sizeof(float), stream);

    convw_kernel       <<<N_EXP * NKB, 256, 0, stream>>>(eW, WTb, counts);
    gate_partial_kernel<<<dim3(T_TOKENS / 64, KSPLIT), 64, 0, stream>>>(x, gW, xbf, partial);
    gate_final_kernel  <<<T_TOKENS / 256, 256, 0, stream>>>(partial, gb, topk_w, topk_e, counts);
    scatter_kernel     <<<S_TOT / (256 * 4), 256, 0, stream>>>(topk_e, topk_w, counts, cursors,
                                                               slot_token, slot_w);
    moe_gemm_kernel<<<S_PAD / 128, 512, 0, stream>>>(xbf, WTb, eb, counts,
                                                     slot_token, slot_w, out);
}

// Round 4
// 261.994 us; speedup vs baseline: 1.1213x; 1.1213x over previous
//
#include <hip/hip_runtime.h>
#include <hip/hip_bf16.h>
#include <stdint.h>

// Problem constants (fixed by reference setup_inputs)
#define T_TOKENS 32768     // 32*1024
#define D_IN     768
#define D_OUT    256
#define N_EXP    8
#define S_TOT    (T_TOKENS*2)   // 65536 routed slots
#define S_PAD    66560          // 65536 + 8*128 worst-case per-expert 128-padding
#define KSPLIT   6              // gate k-split: 768 = 6 x 128
#define NKB      24             // K-blocks of 32 in d_in

typedef __attribute__((ext_vector_type(8))) short bf16x8;
typedef __attribute__((ext_vector_type(4))) float f32x4;

__device__ __forceinline__ unsigned short f2bf(float f) {
    unsigned u = __float_as_uint(f);
    return (unsigned short)((u + 0x7FFFu + ((u >> 16) & 1u)) >> 16);  // RNE
}
__device__ __forceinline__ unsigned pack_bf2(float a, float b) {
    return (unsigned)f2bf(a) | ((unsigned)f2bf(b) << 16);
}

// async global->LDS, 16B per lane. LDS dest must be wave-uniform base + lane*16.
__device__ __forceinline__ void async16(void* lds, const void* g) {
    __builtin_amdgcn_global_load_lds(
        (const __attribute__((address_space(1))) unsigned int*)g,
        (__attribute__((address_space(3))) unsigned int*)lds, 16, 0, 0);
}

// ---- W fp32 [e][k][n] -> bf16 k-blocked [e][kb][n][32kk]; zeroes counts+cursors ----
// Each (e,kb) tile is a contiguous 16 KB slab -> GEMM B reads are fully coalesced.
__global__ __launch_bounds__(256) void convw_kernel(
        const float* __restrict__ W, unsigned short* __restrict__ WTb,
        int* __restrict__ zero16) {
    if (blockIdx.x == 0 && threadIdx.x < 16) zero16[threadIdx.x] = 0;  // counts+cursors
    int eb_ = blockIdx.x;                            // e*NKB + kb, 0..191
    int n = threadIdx.x;
    const float* src = W + ((size_t)(eb_ / NKB) * D_IN + (eb_ % NKB) * 32) * 256 + n;
    unsigned pk[16];
    #pragma unroll
    for (int j = 0; j < 16; j++)                     // reads coalesced (n fastest)
        pk[j] = pack_bf2(src[(2*j) * 256], src[(2*j+1) * 256]);
    unsigned* dst = (unsigned*)(WTb + ((size_t)eb_ * 256 + n) * 32);  // 64 B/thread contig
    #pragma unroll
    for (int j = 0; j < 16; j++) dst[j] = pk[j];
}

// ---- gate stage 1: k-split partial logits. grid=(512,KSPLIT): 64 tokens x 128 k each.
__global__ __launch_bounds__(64) void gate_partial_kernel(
        const float* __restrict__ x, const float* __restrict__ gW,
        unsigned short* __restrict__ xbf, float* __restrict__ partial) {
    __shared__ float tile[64 * 65];
    int tid = threadIdx.x;
    int t0  = blockIdx.x * 64;
    int kq  = blockIdx.y;                            // k-slice 0..KSPLIT-1
    int c16 = tid & 15, rb = tid >> 4;
    float acc[8] = {0,0,0,0,0,0,0,0};
    #pragma unroll 1
    for (int j = 0; j < 2; j++) {
        int kc = kq * 128 + j * 64;
        #pragma unroll
        for (int i = 0; i < 16; i++) {
            int row = i * 4 + rb;
            size_t g = (size_t)(t0 + row) * D_IN + kc + c16 * 4;
            float4 v = *(const float4*)(x + g);
            uint2 p; p.x = pack_bf2(v.x, v.y); p.y = pack_bf2(v.z, v.w);
            *(uint2*)(xbf + g) = p;                  // fused bf16 emit (coalesced 8B)
            float* d = &tile[row * 65 + c16 * 4];
            d[0] = v.x; d[1] = v.y; d[2] = v.z; d[3] = v.w;  // ~2-way banks: free
        }
        __syncthreads();
        const float* gr = gW + (size_t)kc * 8;       // wave-uniform -> s_load
        #pragma unroll 8
        for (int kk = 0; kk < 64; kk++) {
            float xv = tile[tid * 65 + kk];          // bank (l+kk)%32: conflict-free
            #pragma unroll
            for (int e = 0; e < 8; e++) acc[e] += xv * gr[kk * 8 + e];
        }
        __syncthreads();
    }
    float* dst = partial + ((size_t)kq * T_TOKENS + t0 + tid) * 8;
    float4 o0 = {acc[0], acc[1], acc[2], acc[3]};
    float4 o1 = {acc[4], acc[5], acc[6], acc[7]};
    *(float4*)dst = o0; *(float4*)(dst + 4) = o1;    // 32B/token, coalesced
}

// ---- gate stage 2: sum partials (FIXED order: deterministic), softmax, top-2, hist ----
__global__ __launch_bounds__(256) void gate_final_kernel(
        const float* __restrict__ partial, const float* __restrict__ gb,
        float* __restrict__ topk_w, int* __restrict__ topk_e, int* __restrict__ counts) {
    __shared__ int h[8];
    int tid = threadIdx.x;
    if (tid < 8) h[tid] = 0;
    __syncthreads();
    int t = blockIdx.x * 256 + tid;
    float acc[8] = {0,0,0,0,0,0,0,0};
    #pragma unroll
    for (int q = 0; q < KSPLIT; q++) {               // fixed summation order
        const float* p = partial + ((size_t)q * T_TOKENS + t) * 8;
        float4 a = *(const float4*)p;
        float4 b = *(const float4*)(p + 4);
        acc[0] += a.x; acc[1] += a.y; acc[2] += a.z; acc[3] += a.w;
        acc[4] += b.x; acc[5] += b.y; acc[6] += b.z; acc[7] += b.w;
    }
    float mx = -1e30f;
    #pragma unroll
    for (int e = 0; e < 8; e++) { acc[e] += gb[e]; mx = fmaxf(mx, acc[e]); }
    float w[8], s = 0.f;
    #pragma unroll
    for (int e = 0; e < 8; e++) { w[e] = expf(acc[e] - mx); s += w[e]; }
    float inv = 1.0f / s;
    int e0 = 0; float b0 = -1.f;
    #pragma unroll
    for (int e = 0; e < 8; e++) if (w[e] > b0) { b0 = w[e]; e0 = e; }   // ties -> lowest idx
    int e1 = 0; float b1 = -1.f;
    #pragma unroll
    for (int e = 0; e < 8; e++) if (e != e0 && w[e] > b1) { b1 = w[e]; e1 = e; }
    topk_w[t*2]   = b0 * inv;
    topk_w[t*2+1] = b1 * inv;
    topk_e[t*2]   = e0;
    topk_e[t*2+1] = e1;
    atomicAdd(&h[e0], 1); atomicAdd(&h[e1], 1);
    __syncthreads();
    if (tid < 8) atomicAdd(&counts[tid], h[tid]);
}

// ---- scatter (token,w) into expert buckets + inverse map; 128-aligned regions ----
// Block 0 additionally zeroes slot_w over the interior pad gaps (<=127 per expert).
__global__ void scatter_kernel(const int* __restrict__ topk_e, const float* __restrict__ topk_w,
                               const int* __restrict__ counts, int* __restrict__ cursors,
                               int* __restrict__ slot_token, float* __restrict__ slot_w,
                               int* __restrict__ inv_slot) {
    int offs[9]; offs[0] = 0;
    #pragma unroll
    for (int e = 0; e < 8; e++) offs[e+1] = offs[e] + ((counts[e] + 127) & ~127);
    if (blockIdx.x == 0) {                           // zero pad-gap weights
        #pragma unroll
        for (int e = 0; e < 8; e++) {
            int start = offs[e] + counts[e];
            for (int i = start + threadIdx.x; i < offs[e+1]; i += 256) slot_w[i] = 0.f;
        }
    }
    __shared__ int hcnt[8], hbase[8];
    if (threadIdx.x < 8) hcnt[threadIdx.x] = 0;
    __syncthreads();
    int idx[4], ee[4], lr[4];
    int base = blockIdx.x * 256 * 4 + threadIdx.x;
    #pragma unroll
    for (int j = 0; j < 4; j++) {
        idx[j] = base + j * 256;
        ee[j]  = topk_e[idx[j]];
        lr[j]  = atomicAdd(&hcnt[ee[j]], 1);
    }
    __syncthreads();
    if (threadIdx.x < 8) hbase[threadIdx.x] = atomicAdd(&cursors[threadIdx.x], hcnt[threadIdx.x]);
    __syncthreads();
    #pragma unroll
    for (int j = 0; j < 4; j++) {
        int slot = offs[ee[j]] + hbase[ee[j]] + lr[j];
        slot_token[slot] = idx[j] >> 1;
        slot_w[slot]     = topk_w[idx[j]];
        inv_slot[idx[j]] = slot;
    }
}

// ---- routed GEMM, R9: 128x256 tile, 512 thr / 8 waves (2Mx4N), BK=32.
// Change vs R1: B no longer goes through LDS. Each wave's B fragment read from the
// k-blocked WTb tile is a fully-coalesced contiguous 1 KB per instruction, B is 3 MB
// and L2-hot under the XCD swizzle -> load it global->VGPR with a distance-1
// register double-buffer (bA/bB). Only the gathered A stays in the 3-stage
// gload_lds pipeline (1 load/thread/stage, 24 KB LDS total).
// vmcnt discipline (reorder-robust): each iteration issues exactly
// {4 B-loads + 1 A-stage} between asm barriers, so vmcnt(5) at the top guarantees
// stage(s) is complete for ANY intra-iteration ordering; the compiler's own
// waitcnts cover the B registers. Last iter drains with vmcnt(0).
// Rationale: R0-R3 showed the barrier-synced staging pipeline moves ~10 B/cy/CU;
// pulling 2/3 of its bytes (B) out of it and making them wave-private should
// recover the gap. R3 also proved the atomic epilogue costs ~45 us -> back to
// routed stores + separate combine.
template<bool ROUTED>
__global__ __launch_bounds__(512, 4) void moe_gemm_kernel(
        const unsigned short* __restrict__ xbf, const unsigned short* __restrict__ WTb,
        const float* __restrict__ eb, const int* __restrict__ counts,
        const int* __restrict__ slot_token, const float* __restrict__ slot_w,
        float* __restrict__ dst) {
    __shared__ unsigned short A_lds[3][128 * 32];    // 3 x 8 KB = 24 KB total

    // bijective XCD-chunked swizzle: 520 = 8 * 65; consecutive lbid share B panel
    int lbid = (blockIdx.x & 7) * ((int)gridDim.x >> 3) + (blockIdx.x >> 3);

    int offs[9]; offs[0] = 0;
    #pragma unroll
    for (int e = 0; e < 8; e++) offs[e+1] = offs[e] + ((counts[e] + 127) & ~127);
    int row0 = lbid * 128;
    if (row0 >= offs[8]) return;                     // uniform exit (pad tiles)
    int expert = 0;
    #pragma unroll
    for (int e = 0; e < 8; e++) if (row0 >= offs[e]) expert = e;

    int tid  = threadIdx.x;
    int wave = tid >> 6, lane = tid & 63;
    int lrow = lane & 15, lquad = lane >> 4;
    int wm = wave >> 2, wn = wave & 3;               // 2 (M) x 4 (N) wave grid

    // ---- A staging source (LDS dest linear-by-thread; chunk-rotate the SOURCE) ----
    // A: 512 16B-chunks (128 rows x 4) = 1 chunk/thread; gathered rows (row-major xbf)
    int ar = tid >> 2, ap = tid & 3;
    int alc = (ap - (ar >> 1)) & 3;                  // logical chunk at this phys slot
    int tok = slot_token[row0 + ar];
    tok = (tok < 0 || tok >= T_TOKENS) ? 0 : tok;    // pad slots hold garbage: clamp
    const unsigned short* asrc = xbf + (size_t)tok * D_IN + alc * 8;

    // B direct-load base: lane reads logical chunk lquad of row r = wn*64+q*16+lrow
    // within the contiguous 16 KB (kb) tile -> wave covers a contiguous 1 KB block.
    const unsigned short* bptr = WTb + (size_t)expert * NKB * 8192
                                     + (wn * 64 + lrow) * 32 + lquad * 8;

    // A frag LDS offsets (shorts), constant across K
    int a_off[4];
    #pragma unroll
    for (int m = 0; m < 4; m++) {
        int r = wm * 64 + m * 16 + lrow;
        a_off[m] = r * 32 + ((lquad + (r >> 1)) & 3) * 8;
    }

    f32x4 acc[4][4];
    #pragma unroll
    for (int m = 0; m < 4; m++)
        #pragma unroll
        for (int q = 0; q < 4; q++) acc[m][q] = (f32x4){0,0,0,0};

    bf16x8 bA[4], bB[4];
    auto bload = [&](int kb, bf16x8 (&b)[4]) {
        const unsigned short* bp = bptr + (size_t)kb * 8192;
        #pragma unroll
        for (int q = 0; q < 4; q++) b[q] = *(const bf16x8*)(bp + q * 512);
    };

    auto kstep = [&](int s, bf16x8 (&bcur)[4], bf16x8 (&bnxt)[4]) {
        if (s == NKB - 1) asm volatile("s_waitcnt vmcnt(0)" ::: "memory");
        else              asm volatile("s_waitcnt vmcnt(5)" ::: "memory");
        asm volatile("s_barrier" ::: "memory");      // raw: no compiler vmcnt(0) drain
        if (s + 1 < NKB) bload(s + 1, bnxt);         // 4 VMEM (wave-private B regs)
        if (s + 2 < NKB)                             // 1 VMEM (A stage)
            async16(&A_lds[(s + 2) % 3][tid * 8], asrc + (s + 2) * 32);
        int p = s % 3;
        bf16x8 a[4];
        #pragma unroll
        for (int m = 0; m < 4; m++) a[m] = *(const bf16x8*)&A_lds[p][a_off[m]];
        __builtin_amdgcn_s_setprio(1);
        #pragma unroll
        for (int q = 0; q < 4; q++)
            #pragma unroll
            for (int m = 0; m < 4; m++)
                acc[m][q] = __builtin_amdgcn_mfma_f32_16x16x32_bf16(a[m], bcur[q], acc[m][q], 0, 0, 0);
        __builtin_amdgcn_s_setprio(0);
    };

    // prologue: stage(0) MUST be issued first (oldest in vmcnt FIFO)
    async16(&A_lds[0][tid * 8], asrc);
    __builtin_amdgcn_sched_barrier(0);               // pin stage(0) before the rest
    bload(0, bA);
    async16(&A_lds[1][tid * 8], asrc + 32);
    for (int s = 0; s < NKB; s += 2) {               // NKB even
        kstep(s, bA, bB);
        kstep(s + 1, bB, bA);
    }

    // epilogue: D mapping col=lane&15, row=quad*4+reg
    float bias_q[4];
    #pragma unroll
    for (int q = 0; q < 4; q++)
        bias_q[q] = eb[expert * D_OUT + wn * 64 + q * 16 + lrow];
    #pragma unroll
    for (int m = 0; m < 4; m++) {
        #pragma unroll
        for (int r = 0; r < 4; r++) {
            int slot = row0 + wm * 64 + m * 16 + lquad * 4 + r;
            if constexpr (ROUTED) {
                float* drow = dst + (size_t)slot * D_OUT + wn * 64;
                #pragma unroll
                for (int q = 0; q < 4; q++)
                    drow[q * 16 + lrow] = acc[m][q][r] + bias_q[q];
            } else {
                int tk = slot_token[slot];
                float wgt = slot_w[slot];            // pads have wgt=0 (memset path)
                if (wgt != 0.f) {
                    #pragma unroll
                    for (int q = 0; q < 4; q++)
                        atomicAdd(dst + (size_t)tk * D_OUT + wn * 64 + q * 16 + lrow,
                                  wgt * (acc[m][q][r] + bias_q[q]));
                }
            }
        }
    }
}

// ---------------- combine: out[t] = w0*routed[s0] + w1*routed[s1] ----------------
__global__ void combine_kernel(const float* __restrict__ routed, const int* __restrict__ inv_slot,
                               const float* __restrict__ topk_w, float* __restrict__ out) {
    int flat = blockIdx.x * 256 + threadIdx.x;       // float4 index
    int t = flat >> 6, c = (flat & 63) * 4;
    int   s0 = inv_slot[t*2], s1 = inv_slot[t*2+1];
    float w0 = topk_w[t*2],   w1 = topk_w[t*2+1];
    float4 r0 = *(const float4*)(routed + (size_t)s0 * D_OUT + c);
    float4 r1 = *(const float4*)(routed + (size_t)s1 * D_OUT + c);
    float4 o;
    o.x = w0*r0.x + w1*r1.x; o.y = w0*r0.y + w1*r1.y;
    o.z = w0*r0.z + w1*r1.z; o.w = w0*r0.w + w1*r1.w;
    *(float4*)(out + (size_t)t * D_OUT + c) = o;
}

extern "C" void kernel_launch(void* const* d_in, const int* in_sizes, int n_in,
                              void* d_out, int out_size, void* d_ws, size_t ws_size,
                              hipStream_t stream) {
    const float* x  = (const float*)d_in[0];
    const float* gW = (const float*)d_in[1];
    const float* gb = (const float*)d_in[2];
    const float* eW = (const float*)d_in[3];
    const float* eb = (const float*)d_in[4];
    float* out = (float*)d_out;
    char* ws = (char*)d_ws;

    // ws layout
    float* topk_w      = (float*)(ws + 0);                 // 256 KB
    int*   topk_e      = (int*)  (ws + 262144);            // 256 KB
    int*   counts      = (int*)  (ws + 524288);            // 8 ints
    int*   cursors     = (int*)  (ws + 524320);            // 8 ints  (contiguous w/ counts)
    int*   slot_token  = (int*)  (ws + 524416);            // 266240 B (S_PAD)
    float* slot_w      = (float*)(ws + 790656);            // 266240 B (S_PAD)
    int*   inv_slot    = (int*)  (ws + 1056896);           // 262144 B (S_TOT)
    float* partial     = (float*)(ws + 1319040);           // 6 MB  [KSPLIT][T][8] fp32
    unsigned short* WTb= (unsigned short*)(ws + 7610496);  // 3 MB bf16 W k-blocked
    unsigned short* xbf= (unsigned short*)(ws + 10756224); // 48 MB bf16 x
    float* routed      = (float*)(ws + 61087872);          // 68 MB routed outputs
    const size_t NEED_ROUTED = 61087872 + (size_t)S_PAD * D_OUT * 4;  // ~129 MB
    bool use_routed = (ws_size >= NEED_ROUTED);

    convw_kernel       <<<N_EXP * NKB, 256, 0, stream>>>(eW, WTb, counts);
    gate_partial_kernel<<<dim3(T_TOKENS / 64, KSPLIT), 64, 0, stream>>>(x, gW, xbf, partial);
    gate_final_kernel  <<<T_TOKENS / 256, 256, 0, stream>>>(partial, gb, topk_w, topk_e, counts);
    scatter_kernel     <<<S_TOT / (256 * 4), 256, 0, stream>>>(topk_e, topk_w, counts, cursors,
                                                               slot_token, slot_w, inv_slot);
    if (use_routed) {
        moe_gemm_kernel<true><<<S_PAD / 128, 512, 0, stream>>>(xbf, WTb, eb, counts,
                                                               slot_token, slot_w, routed);
        combine_kernel<<<T_TOKENS * D_OUT / 4 / 256, 256, 0, stream>>>(routed, inv_slot,
                                                                       topk_w, out);
    } else {
        // fallback: pads must be (token=0, w=0) for the atomic path
        hipMemsetAsync(slot_token, 0, 532480, stream);
        hipMemsetAsync(out, 0, (size_t)out_size * sizeof(float), stream);
        moe_gemm_kernel<false><<<S_PAD / 128, 512, 0, stream>>>(xbf, WTb, eb, counts,
                                                                slot_token, slot_w, out);
    }
}

// Round 5
// 255.518 us; speedup vs baseline: 1.1498x; 1.0253x over previous
//
#include <hip/hip_runtime.h>
#include <hip/hip_bf16.h>
#include <stdint.h>

// Problem constants (fixed by reference setup_inputs)
#define T_TOKENS 32768     // 32*1024
#define D_IN     768
#define D_OUT    256
#define N_EXP    8
#define S_TOT    (T_TOKENS*2)   // 65536 routed slots
#define S_PAD    66560          // 65536 + 8*128 worst-case per-expert 128-padding
#define NKB      24             // K-blocks of 32 in d_in

typedef __attribute__((ext_vector_type(8))) short bf16x8;
typedef __attribute__((ext_vector_type(4))) float f32x4;

__device__ __forceinline__ unsigned short f2bf(float f) {
    unsigned u = __float_as_uint(f);
    return (unsigned short)((u + 0x7FFFu + ((u >> 16) & 1u)) >> 16);  // RNE
}
__device__ __forceinline__ unsigned pack_bf2(float a, float b) {
    return (unsigned)f2bf(a) | ((unsigned)f2bf(b) << 16);
}

// async global->LDS, 16B per lane. LDS dest must be wave-uniform base + lane*16.
__device__ __forceinline__ void async16(void* lds, const void* g) {
    __builtin_amdgcn_global_load_lds(
        (const __attribute__((address_space(1))) unsigned int*)g,
        (__attribute__((address_space(3))) unsigned int*)lds, 16, 0, 0);
}

// ---- W fp32 [e][k][n] -> bf16 k-blocked [e][kb][n][32kk]; zeroes counts+cursors ----
// Each (e,kb) tile is a contiguous 16 KB slab -> GEMM B reads are fully coalesced.
__global__ __launch_bounds__(256) void convw_kernel(
        const float* __restrict__ W, unsigned short* __restrict__ WTb,
        int* __restrict__ zero16) {
    if (blockIdx.x == 0 && threadIdx.x < 16) zero16[threadIdx.x] = 0;  // counts+cursors
    int eb_ = blockIdx.x;                            // e*NKB + kb, 0..191
    int n = threadIdx.x;
    const float* src = W + ((size_t)(eb_ / NKB) * D_IN + (eb_ % NKB) * 32) * 256 + n;
    unsigned pk[16];
    #pragma unroll
    for (int j = 0; j < 16; j++)                     // reads coalesced (n fastest)
        pk[j] = pack_bf2(src[(2*j) * 256], src[(2*j+1) * 256]);
    unsigned* dst = (unsigned*)(WTb + ((size_t)eb_ * 256 + n) * 32);  // 64 B/thread contig
    #pragma unroll
    for (int j = 0; j < 16; j++) dst[j] = pk[j];
}

// ---- FUSED gate: x->bf16 emit + full 768-K logits + softmax + top-2 + histogram ----
// R5: replaces gate_partial (62.6 us, 1-wave blocks, 21% HBM) + gate_final (+6 us)
// + the 12 MB partial round-trip. 1024 blocks x 256 thr (4 waves), 32 tokens/block,
// 6 chunks of 128 k. Per chunk: coalesced fp32 loads -> fused xbf emit -> LDS tile
// (stride 133: compute reads ~2-way banks) + 4 KB contiguous gW slice (8-lane
// broadcast reads). Compute: 8 threads/token, k = qq + 8*kk -> shfl_xor(1,2,4)
// reduce; lane qq==0 finalizes (same tie rules as old gate_final: strict >, lowest
// index wins). LDS 21.3 KB -> all 4 blocks/CU co-resident, uniform work, no tail.
__global__ __launch_bounds__(256) void gate_fused_kernel(
        const float* __restrict__ x, const float* __restrict__ gW,
        const float* __restrict__ gb, unsigned short* __restrict__ xbf,
        float* __restrict__ topk_w, int* __restrict__ topk_e,
        int* __restrict__ counts) {
    __shared__ float tile[32 * 133];                 // 17.0 KB
    __shared__ float gws[1024];                      // 4 KB gW k-slice [128][8]
    __shared__ int h8[8];
    int tid = threadIdx.x;
    if (tid < 8) h8[tid] = 0;                        // first barrier (ch=0) covers this
    int t0 = blockIdx.x * 32;
    int kf = tid & 31, rb = tid >> 5;                // load map: 32 k-float4 x 8 rows
    int tt = tid >> 3, qq = tid & 7;                 // compute map: token x k-eighth
    float acc[8] = {0,0,0,0,0,0,0,0};
    #pragma unroll 1
    for (int ch = 0; ch < 6; ++ch) {
        int kc = ch * 128;
        __syncthreads();                             // tile/gws free from prev compute
        *(float4*)&gws[tid * 4] = *(const float4*)(gW + kc * 8 + tid * 4);  // contig 4KB
        #pragma unroll
        for (int i = 0; i < 4; ++i) {
            int row = i * 8 + rb;
            size_t g = (size_t)(t0 + row) * D_IN + kc + kf * 4;
            float4 v = *(const float4*)(x + g);      // 512B segments, coalesced
            uint2 p; p.x = pack_bf2(v.x, v.y); p.y = pack_bf2(v.z, v.w);
            *(uint2*)(xbf + g) = p;                  // fused bf16 emit (coalesced 8B)
            float* d = &tile[row * 133 + kf * 4];
            d[0] = v.x; d[1] = v.y; d[2] = v.z; d[3] = v.w;
        }
        __syncthreads();
        #pragma unroll
        for (int kk = 0; kk < 16; ++kk) {
            float xv = tile[tt * 133 + qq + 8 * kk]; // banks (5tt+qq+8kk)%32: ~2-way
            const float* gp = &gws[(qq + 8 * kk) * 8];  // 8 addrs, broadcast over tt
            #pragma unroll
            for (int e = 0; e < 8; ++e) acc[e] += xv * gp[e];
        }
    }
    #pragma unroll
    for (int e = 0; e < 8; ++e) {                    // fixed-order 8-lane reduce
        acc[e] += __shfl_xor(acc[e], 1);
        acc[e] += __shfl_xor(acc[e], 2);
        acc[e] += __shfl_xor(acc[e], 4);
    }
    if (qq == 0) {
        int t = t0 + tt;
        float mx = -1e30f;
        #pragma unroll
        for (int e = 0; e < 8; ++e) { acc[e] += gb[e]; mx = fmaxf(mx, acc[e]); }
        float w[8], s = 0.f;
        #pragma unroll
        for (int e = 0; e < 8; ++e) { w[e] = expf(acc[e] - mx); s += w[e]; }
        float inv = 1.0f / s;
        int e0 = 0; float b0 = -1.f;
        #pragma unroll
        for (int e = 0; e < 8; ++e) if (w[e] > b0) { b0 = w[e]; e0 = e; }
        int e1 = 0; float b1 = -1.f;
        #pragma unroll
        for (int e = 0; e < 8; ++e) if (e != e0 && w[e] > b1) { b1 = w[e]; e1 = e; }
        topk_w[t*2]   = b0 * inv;
        topk_w[t*2+1] = b1 * inv;
        topk_e[t*2]   = e0;
        topk_e[t*2+1] = e1;
        atomicAdd(&h8[e0], 1); atomicAdd(&h8[e1], 1);
    }
    __syncthreads();
    if (tid < 8) atomicAdd(&counts[tid], h8[tid]);
}

// ---- scatter (token,w) into expert buckets + inverse map; 128-aligned regions ----
// Block 0 additionally zeroes slot_w over the interior pad gaps (<=127 per expert).
__global__ void scatter_kernel(const int* __restrict__ topk_e, const float* __restrict__ topk_w,
                               const int* __restrict__ counts, int* __restrict__ cursors,
                               int* __restrict__ slot_token, float* __restrict__ slot_w,
                               int* __restrict__ inv_slot) {
    int offs[9]; offs[0] = 0;
    #pragma unroll
    for (int e = 0; e < 8; e++) offs[e+1] = offs[e] + ((counts[e] + 127) & ~127);
    if (blockIdx.x == 0) {                           // zero pad-gap weights
        #pragma unroll
        for (int e = 0; e < 8; e++) {
            int start = offs[e] + counts[e];
            for (int i = start + threadIdx.x; i < offs[e+1]; i += 256) slot_w[i] = 0.f;
        }
    }
    __shared__ int hcnt[8], hbase[8];
    if (threadIdx.x < 8) hcnt[threadIdx.x] = 0;
    __syncthreads();
    int idx[4], ee[4], lr[4];
    int base = blockIdx.x * 256 * 4 + threadIdx.x;
    #pragma unroll
    for (int j = 0; j < 4; j++) {
        idx[j] = base + j * 256;
        ee[j]  = topk_e[idx[j]];
        lr[j]  = atomicAdd(&hcnt[ee[j]], 1);
    }
    __syncthreads();
    if (threadIdx.x < 8) hbase[threadIdx.x] = atomicAdd(&cursors[threadIdx.x], hcnt[threadIdx.x]);
    __syncthreads();
    #pragma unroll
    for (int j = 0; j < 4; j++) {
        int slot = offs[ee[j]] + hbase[ee[j]] + lr[j];
        slot_token[slot] = idx[j] >> 1;
        slot_w[slot]     = topk_w[idx[j]];
        inv_slot[idx[j]] = slot;
    }
}

// ---- routed GEMM (unchanged from R4): 128x256 tile, 512 thr / 8 waves (2Mx4N),
// BK=32, B global->VGPR dist-1 double-buffer, A via 3-stage gload_lds, 24 KB LDS.
template<bool ROUTED>
__global__ __launch_bounds__(512, 4) void moe_gemm_kernel(
        const unsigned short* __restrict__ xbf, const unsigned short* __restrict__ WTb,
        const float* __restrict__ eb, const int* __restrict__ counts,
        const int* __restrict__ slot_token, const float* __restrict__ slot_w,
        float* __restrict__ dst) {
    __shared__ unsigned short A_lds[3][128 * 32];    // 3 x 8 KB = 24 KB total

    // bijective XCD-chunked swizzle: 520 = 8 * 65; consecutive lbid share B panel
    int lbid = (blockIdx.x & 7) * ((int)gridDim.x >> 3) + (blockIdx.x >> 3);

    int offs[9]; offs[0] = 0;
    #pragma unroll
    for (int e = 0; e < 8; e++) offs[e+1] = offs[e] + ((counts[e] + 127) & ~127);
    int row0 = lbid * 128;
    if (row0 >= offs[8]) return;                     // uniform exit (pad tiles)
    int expert = 0;
    #pragma unroll
    for (int e = 0; e < 8; e++) if (row0 >= offs[e]) expert = e;

    int tid  = threadIdx.x;
    int wave = tid >> 6, lane = tid & 63;
    int lrow = lane & 15, lquad = lane >> 4;
    int wm = wave >> 2, wn = wave & 3;               // 2 (M) x 4 (N) wave grid

    // A: 512 16B-chunks (128 rows x 4) = 1 chunk/thread; gathered rows (row-major xbf)
    int ar = tid >> 2, ap = tid & 3;
    int alc = (ap - (ar >> 1)) & 3;                  // logical chunk at this phys slot
    int tok = slot_token[row0 + ar];
    tok = (tok < 0 || tok >= T_TOKENS) ? 0 : tok;    // pad slots hold garbage: clamp
    const unsigned short* asrc = xbf + (size_t)tok * D_IN + alc * 8;

    // B direct-load base: wave covers a contiguous 1 KB block per q.
    const unsigned short* bptr = WTb + (size_t)expert * NKB * 8192
                                     + (wn * 64 + lrow) * 32 + lquad * 8;

    // A frag LDS offsets (shorts), constant across K
    int a_off[4];
    #pragma unroll
    for (int m = 0; m < 4; m++) {
        int r = wm * 64 + m * 16 + lrow;
        a_off[m] = r * 32 + ((lquad + (r >> 1)) & 3) * 8;
    }

    f32x4 acc[4][4];
    #pragma unroll
    for (int m = 0; m < 4; m++)
        #pragma unroll
        for (int q = 0; q < 4; q++) acc[m][q] = (f32x4){0,0,0,0};

    bf16x8 bA[4], bB[4];
    auto bload = [&](int kb, bf16x8 (&b)[4]) {
        const unsigned short* bp = bptr + (size_t)kb * 8192;
        #pragma unroll
        for (int q = 0; q < 4; q++) b[q] = *(const bf16x8*)(bp + q * 512);
    };

    auto kstep = [&](int s, bf16x8 (&bcur)[4], bf16x8 (&bnxt)[4]) {
        if (s == NKB - 1) asm volatile("s_waitcnt vmcnt(0)" ::: "memory");
        else              asm volatile("s_waitcnt vmcnt(5)" ::: "memory");
        asm volatile("s_barrier" ::: "memory");      // raw: no compiler vmcnt(0) drain
        if (s + 1 < NKB) bload(s + 1, bnxt);         // 4 VMEM (wave-private B regs)
        if (s + 2 < NKB)                             // 1 VMEM (A stage)
            async16(&A_lds[(s + 2) % 3][tid * 8], asrc + (s + 2) * 32);
        int p = s % 3;
        bf16x8 a[4];
        #pragma unroll
        for (int m = 0; m < 4; m++) a[m] = *(const bf16x8*)&A_lds[p][a_off[m]];
        __builtin_amdgcn_s_setprio(1);
        #pragma unroll
        for (int q = 0; q < 4; q++)
            #pragma unroll
            for (int m = 0; m < 4; m++)
                acc[m][q] = __builtin_amdgcn_mfma_f32_16x16x32_bf16(a[m], bcur[q], acc[m][q], 0, 0, 0);
        __builtin_amdgcn_s_setprio(0);
    };

    // prologue: stage(0) MUST be issued first (oldest in vmcnt FIFO)
    async16(&A_lds[0][tid * 8], asrc);
    __builtin_amdgcn_sched_barrier(0);               // pin stage(0) before the rest
    bload(0, bA);
    async16(&A_lds[1][tid * 8], asrc + 32);
    for (int s = 0; s < NKB; s += 2) {               // NKB even
        kstep(s, bA, bB);
        kstep(s + 1, bB, bA);
    }

    // epilogue: D mapping col=lane&15, row=quad*4+reg
    float bias_q[4];
    #pragma unroll
    for (int q = 0; q < 4; q++)
        bias_q[q] = eb[expert * D_OUT + wn * 64 + q * 16 + lrow];
    #pragma unroll
    for (int m = 0; m < 4; m++) {
        #pragma unroll
        for (int r = 0; r < 4; r++) {
            int slot = row0 + wm * 64 + m * 16 + lquad * 4 + r;
            if constexpr (ROUTED) {
                float* drow = dst + (size_t)slot * D_OUT + wn * 64;
                #pragma unroll
                for (int q = 0; q < 4; q++)
                    drow[q * 16 + lrow] = acc[m][q][r] + bias_q[q];
            } else {
                int tk = slot_token[slot];
                float wgt = slot_w[slot];            // pads have wgt=0 (memset path)
                if (wgt != 0.f) {
                    #pragma unroll
                    for (int q = 0; q < 4; q++)
                        atomicAdd(dst + (size_t)tk * D_OUT + wn * 64 + q * 16 + lrow,
                                  wgt * (acc[m][q][r] + bias_q[q]));
                }
            }
        }
    }
}

// ---------------- combine: out[t] = w0*routed[s0] + w1*routed[s1] ----------------
__global__ void combine_kernel(const float* __restrict__ routed, const int* __restrict__ inv_slot,
                               const float* __restrict__ topk_w, float* __restrict__ out) {
    int flat = blockIdx.x * 256 + threadIdx.x;       // float4 index
    int t = flat >> 6, c = (flat & 63) * 4;
    int   s0 = inv_slot[t*2], s1 = inv_slot[t*2+1];
    float w0 = topk_w[t*2],   w1 = topk_w[t*2+1];
    float4 r0 = *(const float4*)(routed + (size_t)s0 * D_OUT + c);
    float4 r1 = *(const float4*)(routed + (size_t)s1 * D_OUT + c);
    float4 o;
    o.x = w0*r0.x + w1*r1.x; o.y = w0*r0.y + w1*r1.y;
    o.z = w0*r0.z + w1*r1.z; o.w = w0*r0.w + w1*r1.w;
    *(float4*)(out + (size_t)t * D_OUT + c) = o;
}

extern "C" void kernel_launch(void* const* d_in, const int* in_sizes, int n_in,
                              void* d_out, int out_size, void* d_ws, size_t ws_size,
                              hipStream_t stream) {
    const float* x  = (const float*)d_in[0];
    const float* gW = (const float*)d_in[1];
    const float* gb = (const float*)d_in[2];
    const float* eW = (const float*)d_in[3];
    const float* eb = (const float*)d_in[4];
    float* out = (float*)d_out;
    char* ws = (char*)d_ws;

    // ws layout
    float* topk_w      = (float*)(ws + 0);                 // 256 KB
    int*   topk_e      = (int*)  (ws + 262144);            // 256 KB
    int*   counts      = (int*)  (ws + 524288);            // 8 ints
    int*   cursors     = (int*)  (ws + 524320);            // 8 ints  (contiguous w/ counts)
    int*   slot_token  = (int*)  (ws + 524416);            // 266240 B (S_PAD)
    float* slot_w      = (float*)(ws + 790656);            // 266240 B (S_PAD)
    int*   inv_slot    = (int*)  (ws + 1056896);           // 262144 B (S_TOT)
    unsigned short* WTb= (unsigned short*)(ws + 7610496);  // 3 MB bf16 W k-blocked
    unsigned short* xbf= (unsigned short*)(ws + 10756224); // 48 MB bf16 x
    float* routed      = (float*)(ws + 61087872);          // 68 MB routed outputs
    const size_t NEED_ROUTED = 61087872 + (size_t)S_PAD * D_OUT * 4;  // ~129 MB
    bool use_routed = (ws_size >= NEED_ROUTED);

    convw_kernel      <<<N_EXP * NKB, 256, 0, stream>>>(eW, WTb, counts);
    gate_fused_kernel <<<T_TOKENS / 32, 256, 0, stream>>>(x, gW, gb, xbf,
                                                          topk_w, topk_e, counts);
    scatter_kernel    <<<S_TOT / (256 * 4), 256, 0, stream>>>(topk_e, topk_w, counts, cursors,
                                                              slot_token, slot_w, inv_slot);
    if (use_routed) {
        moe_gemm_kernel<true><<<S_PAD / 128, 512, 0, stream>>>(xbf, WTb, eb, counts,
                                                               slot_token, slot_w, routed);
        combine_kernel<<<T_TOKENS * D_OUT / 4 / 256, 256, 0, stream>>>(routed, inv_slot,
                                                                       topk_w, out);
    } else {
        // fallback: pads must be (token=0, w=0) for the atomic path
        hipMemsetAsync(slot_token, 0, 532480, stream);
        hipMemsetAsync(out, 0, (size_t)out_size * sizeof(float), stream);
        moe_gemm_kernel<false><<<S_PAD / 128, 512, 0, stream>>>(xbf, WTb, eb, counts,
                                                                slot_token, slot_w, out);
    }
}

// Round 6
// 248.519 us; speedup vs baseline: 1.1821x; 1.0282x over previous
//
#include <hip/hip_runtime.h>
#include <hip/hip_bf16.h>
#include <stdint.h>

// Problem constants (fixed by reference setup_inputs)
#define T_TOKENS 32768     // 32*1024
#define D_IN     768
#define D_OUT    256
#define N_EXP    8
#define S_TOT    (T_TOKENS*2)   // 65536 routed slots
#define S_PAD    66560          // 65536 + 8*128 worst-case per-expert 128-padding
#define NKB      24             // K-blocks of 32 in d_in

typedef __attribute__((ext_vector_type(8))) short bf16x8;
typedef __attribute__((ext_vector_type(4))) float f32x4;

__device__ __forceinline__ unsigned short f2bf(float f) {
    unsigned u = __float_as_uint(f);
    return (unsigned short)((u + 0x7FFFu + ((u >> 16) & 1u)) >> 16);  // RNE
}
__device__ __forceinline__ unsigned pack_bf2(float a, float b) {
    return (unsigned)f2bf(a) | ((unsigned)f2bf(b) << 16);
}

// async global->LDS, 16B per lane. LDS dest must be wave-uniform base + lane*16.
__device__ __forceinline__ void async16(void* lds, const void* g) {
    __builtin_amdgcn_global_load_lds(
        (const __attribute__((address_space(1))) unsigned int*)g,
        (__attribute__((address_space(3))) unsigned int*)lds, 16, 0, 0);
}

// ---- W fp32 [e][k][n] -> bf16 k-blocked [e][kb][n][32kk]; zeroes counts+cursors ----
// Each (e,kb) tile is a contiguous 16 KB slab -> GEMM B reads are fully coalesced.
__global__ __launch_bounds__(256) void convw_kernel(
        const float* __restrict__ W, unsigned short* __restrict__ WTb,
        int* __restrict__ zero16) {
    if (blockIdx.x == 0 && threadIdx.x < 16) zero16[threadIdx.x] = 0;  // counts+cursors
    int eb_ = blockIdx.x;                            // e*NKB + kb, 0..191
    int n = threadIdx.x;
    const float* src = W + ((size_t)(eb_ / NKB) * D_IN + (eb_ % NKB) * 32) * 256 + n;
    unsigned pk[16];
    #pragma unroll
    for (int j = 0; j < 16; j++)                     // reads coalesced (n fastest)
        pk[j] = pack_bf2(src[(2*j) * 256], src[(2*j+1) * 256]);
    unsigned* dst = (unsigned*)(WTb + ((size_t)eb_ * 256 + n) * 32);  // 64 B/thread contig
    #pragma unroll
    for (int j = 0; j < 16; j++) dst[j] = pk[j];
}

// ---- FUSED gate: x->bf16 emit + full 768-K logits + softmax + top-2 + histogram ----
// R6 change: gW LDS reads vectorized (float4): inner loop = 1 b32 + 2 b128 per 8 MACs
// instead of 1+8 b32 -> per-thread DS instructions 864 -> 288 (gate was LDS-pipe
// bound: HBM only ~21%, VALU ~8%). g0/g1 b128: lanes share addr across tt
// (broadcast), qq vs qq+4 collide 2-way (free-ish).
__global__ __launch_bounds__(256) void gate_fused_kernel(
        const float* __restrict__ x, const float* __restrict__ gW,
        const float* __restrict__ gb, unsigned short* __restrict__ xbf,
        float* __restrict__ topk_w, int* __restrict__ topk_e,
        int* __restrict__ counts) {
    __shared__ float tile[32 * 133];                 // 17.0 KB
    __shared__ float4 gws4[256];                     // 4 KB gW k-slice [128][8] as f4x2
    __shared__ int h8[8];
    int tid = threadIdx.x;
    if (tid < 8) h8[tid] = 0;                        // first barrier (ch=0) covers this
    int t0 = blockIdx.x * 32;
    int kf = tid & 31, rb = tid >> 5;                // load map: 32 k-float4 x 8 rows
    int tt = tid >> 3, qq = tid & 7;                 // compute map: token x k-eighth
    float acc[8] = {0,0,0,0,0,0,0,0};
    #pragma unroll 1
    for (int ch = 0; ch < 6; ++ch) {
        int kc = ch * 128;
        __syncthreads();                             // tile/gws free from prev compute
        gws4[tid] = *(const float4*)(gW + kc * 8 + tid * 4);  // contig 4KB
        #pragma unroll
        for (int i = 0; i < 4; ++i) {
            int row = i * 8 + rb;
            size_t g = (size_t)(t0 + row) * D_IN + kc + kf * 4;
            float4 v = *(const float4*)(x + g);      // 512B segments, coalesced
            uint2 p; p.x = pack_bf2(v.x, v.y); p.y = pack_bf2(v.z, v.w);
            *(uint2*)(xbf + g) = p;                  // fused bf16 emit (coalesced 8B)
            float* d = &tile[row * 133 + kf * 4];
            d[0] = v.x; d[1] = v.y; d[2] = v.z; d[3] = v.w;
        }
        __syncthreads();
        #pragma unroll
        for (int kk = 0; kk < 16; ++kk) {
            float xv = tile[tt * 133 + qq + 8 * kk]; // banks (5tt+qq+8kk)%32: ~2-way
            float4 g0 = gws4[(qq + 8 * kk) * 2];
            float4 g1 = gws4[(qq + 8 * kk) * 2 + 1];
            acc[0] += xv * g0.x; acc[1] += xv * g0.y;
            acc[2] += xv * g0.z; acc[3] += xv * g0.w;
            acc[4] += xv * g1.x; acc[5] += xv * g1.y;
            acc[6] += xv * g1.z; acc[7] += xv * g1.w;
        }
    }
    #pragma unroll
    for (int e = 0; e < 8; ++e) {                    // fixed-order 8-lane reduce
        acc[e] += __shfl_xor(acc[e], 1);
        acc[e] += __shfl_xor(acc[e], 2);
        acc[e] += __shfl_xor(acc[e], 4);
    }
    if (qq == 0) {
        int t = t0 + tt;
        float mx = -1e30f;
        #pragma unroll
        for (int e = 0; e < 8; ++e) { acc[e] += gb[e]; mx = fmaxf(mx, acc[e]); }
        float w[8], s = 0.f;
        #pragma unroll
        for (int e = 0; e < 8; ++e) { w[e] = expf(acc[e] - mx); s += w[e]; }
        float inv = 1.0f / s;
        int e0 = 0; float b0 = -1.f;
        #pragma unroll
        for (int e = 0; e < 8; ++e) if (w[e] > b0) { b0 = w[e]; e0 = e; }
        int e1 = 0; float b1 = -1.f;
        #pragma unroll
        for (int e = 0; e < 8; ++e) if (e != e0 && w[e] > b1) { b1 = w[e]; e1 = e; }
        topk_w[t*2]   = b0 * inv;
        topk_w[t*2+1] = b1 * inv;
        topk_e[t*2]   = e0;
        topk_e[t*2+1] = e1;
        atomicAdd(&h8[e0], 1); atomicAdd(&h8[e1], 1);
    }
    __syncthreads();
    if (tid < 8) atomicAdd(&counts[tid], h8[tid]);
}

// ---- scatter (token,w) into expert buckets + inverse map; 128-aligned regions ----
// Block 0 additionally zeroes slot_w over the interior pad gaps (<=127 per expert).
__global__ void scatter_kernel(const int* __restrict__ topk_e, const float* __restrict__ topk_w,
                               const int* __restrict__ counts, int* __restrict__ cursors,
                               int* __restrict__ slot_token, float* __restrict__ slot_w,
                               int* __restrict__ inv_slot) {
    int offs[9]; offs[0] = 0;
    #pragma unroll
    for (int e = 0; e < 8; e++) offs[e+1] = offs[e] + ((counts[e] + 127) & ~127);
    if (blockIdx.x == 0) {                           // zero pad-gap weights
        #pragma unroll
        for (int e = 0; e < 8; e++) {
            int start = offs[e] + counts[e];
            for (int i = start + threadIdx.x; i < offs[e+1]; i += 256) slot_w[i] = 0.f;
        }
    }
    __shared__ int hcnt[8], hbase[8];
    if (threadIdx.x < 8) hcnt[threadIdx.x] = 0;
    __syncthreads();
    int idx[4], ee[4], lr[4];
    int base = blockIdx.x * 256 * 4 + threadIdx.x;
    #pragma unroll
    for (int j = 0; j < 4; j++) {
        idx[j] = base + j * 256;
        ee[j]  = topk_e[idx[j]];
        lr[j]  = atomicAdd(&hcnt[ee[j]], 1);
    }
    __syncthreads();
    if (threadIdx.x < 8) hbase[threadIdx.x] = atomicAdd(&cursors[threadIdx.x], hcnt[threadIdx.x]);
    __syncthreads();
    #pragma unroll
    for (int j = 0; j < 4; j++) {
        int slot = offs[ee[j]] + hbase[ee[j]] + lr[j];
        slot_token[slot] = idx[j] >> 1;
        slot_w[slot]     = topk_w[idx[j]];
        inv_slot[idx[j]] = slot;
    }
}

// ---- routed GEMM, R6: 128x256 tile, 512 thr / 8 waves in 1M x 8N grid.
// Each wave owns ALL 128 rows x a 32-col slice -> B fragments loaded exactly once
// per tile (2 loads/wave/step): B VMEM 400 MB (R4's 2x wm-duplication) -> 200 MB.
// Counter evidence for the change: R4 issued ~500 MB VMEM in 63 us = ~13 B/cy/CU =
// the per-CU VMEM port ceiling; MfmaUtil 15.7, HBM 24% -> byte-bound at the port.
// A stays in the 3-stage gload_lds pipeline (1 VMEM/thread/step, 24 KB LDS);
// per-step issues {2 B-loads, 1 A-stage} -> counted vmcnt(3) forces stage(s) only.
// a-frags read in two groups of 4 (8 b128/wave/step; LDS has ~20x the per-byte
// headroom of the VMEM port) to keep VGPR <= 128 for 2 blocks/CU.
template<bool ROUTED>
__global__ __launch_bounds__(512, 4) void moe_gemm_kernel(
        const unsigned short* __restrict__ xbf, const unsigned short* __restrict__ WTb,
        const float* __restrict__ eb, const int* __restrict__ counts,
        const int* __restrict__ slot_token, const float* __restrict__ slot_w,
        float* __restrict__ dst) {
    __shared__ unsigned short A_lds[3][128 * 32];    // 3 x 8 KB = 24 KB total

    // bijective XCD-chunked swizzle: 520 = 8 * 65; consecutive lbid share B panel
    int lbid = (blockIdx.x & 7) * ((int)gridDim.x >> 3) + (blockIdx.x >> 3);

    int offs[9]; offs[0] = 0;
    #pragma unroll
    for (int e = 0; e < 8; e++) offs[e+1] = offs[e] + ((counts[e] + 127) & ~127);
    int row0 = lbid * 128;
    if (row0 >= offs[8]) return;                     // uniform exit (pad tiles)
    int expert = 0;
    #pragma unroll
    for (int e = 0; e < 8; e++) if (row0 >= offs[e]) expert = e;

    int tid  = threadIdx.x;
    int wave = tid >> 6, lane = tid & 63;
    int lrow = lane & 15, lquad = lane >> 4;
    int wn = wave;                                   // 1 (M) x 8 (N) wave grid

    // A: 512 16B-chunks (128 rows x 4) = 1 chunk/thread; gathered rows (row-major xbf)
    int ar = tid >> 2, ap = tid & 3;
    int alc = (ap - (ar >> 1)) & 3;                  // logical chunk at this phys slot
    int tok = slot_token[row0 + ar];
    tok = (tok < 0 || tok >= T_TOKENS) ? 0 : tok;    // pad slots hold garbage: clamp
    const unsigned short* asrc = xbf + (size_t)tok * D_IN + alc * 8;

    // B direct-load base: wave covers contiguous 1 KB per q (16 rows x 4 lquad chunks)
    const unsigned short* bptr = WTb + (size_t)expert * NKB * 8192
                                     + (wn * 32 + lrow) * 32 + lquad * 8;

    // A frag LDS offsets (shorts), constant across K; every wave reads all 128 rows
    int a_off[8];
    #pragma unroll
    for (int m = 0; m < 8; m++) {
        int r = m * 16 + lrow;
        a_off[m] = r * 32 + ((lquad + (r >> 1)) & 3) * 8;
    }

    f32x4 acc[8][2];
    #pragma unroll
    for (int m = 0; m < 8; m++)
        #pragma unroll
        for (int q = 0; q < 2; q++) acc[m][q] = (f32x4){0,0,0,0};

    bf16x8 bA[2], bB[2];
    auto bload = [&](int kb, bf16x8 (&b)[2]) {
        const unsigned short* bp = bptr + (size_t)kb * 8192;
        #pragma unroll
        for (int q = 0; q < 2; q++) b[q] = *(const bf16x8*)(bp + q * 512);
    };

    int rd = 0, wr = 2;                              // A stage read/write cursors
    auto kstep = [&](int s, bf16x8 (&bcur)[2], bf16x8 (&bnxt)[2]) {
        // FIFO at top of step s: [A(s), B(s)x2, A(s+1)] -> vmcnt(3) forces A(s).
        // Compiler inserts its own wait for bcur regs before the MFMAs.
        if (s == NKB - 1) asm volatile("s_waitcnt vmcnt(0)" ::: "memory");
        else              asm volatile("s_waitcnt vmcnt(3)" ::: "memory");
        asm volatile("s_barrier" ::: "memory");      // raw: no compiler vmcnt(0) drain
        if (s + 1 < NKB) bload(s + 1, bnxt);         // 2 VMEM (wave-private B regs)
        if (s + 2 < NKB)                             // 1 VMEM (A stage)
            async16(&A_lds[wr][tid * 8], asrc + (s + 2) * 32);
        #pragma unroll
        for (int g = 0; g < 2; ++g) {                // a-frags in 2 groups of 4
            bf16x8 a[4];
            #pragma unroll
            for (int m = 0; m < 4; ++m) a[m] = *(const bf16x8*)&A_lds[rd][a_off[g*4+m]];
            __builtin_amdgcn_s_setprio(1);
            #pragma unroll
            for (int q = 0; q < 2; ++q)
                #pragma unroll
                for (int m = 0; m < 4; ++m)
                    acc[g*4+m][q] = __builtin_amdgcn_mfma_f32_16x16x32_bf16(
                        a[m], bcur[q], acc[g*4+m][q], 0, 0, 0);
            __builtin_amdgcn_s_setprio(0);
        }
        rd = rd == 2 ? 0 : rd + 1;
        wr = wr == 2 ? 0 : wr + 1;
    };

    // prologue: A(0), A(1) oldest in vmcnt FIFO, then B(0)
    async16(&A_lds[0][tid * 8], asrc);
    async16(&A_lds[1][tid * 8], asrc + 32);
    __builtin_amdgcn_sched_barrier(0);               // pin A stages before bload
    bload(0, bA);
    for (int s = 0; s < NKB; s += 2) {               // NKB even
        kstep(s, bA, bB);
        kstep(s + 1, bB, bA);
    }

    // epilogue: D mapping col=lane&15, row=quad*4+reg
    float bias_q[2];
    #pragma unroll
    for (int q = 0; q < 2; q++)
        bias_q[q] = eb[expert * D_OUT + wn * 32 + q * 16 + lrow];
    #pragma unroll
    for (int m = 0; m < 8; m++) {
        #pragma unroll
        for (int r = 0; r < 4; r++) {
            int slot = row0 + m * 16 + lquad * 4 + r;
            if constexpr (ROUTED) {
                float* drow = dst + (size_t)slot * D_OUT + wn * 32;
                #pragma unroll
                for (int q = 0; q < 2; q++)
                    drow[q * 16 + lrow] = acc[m][q][r] + bias_q[q];
            } else {
                int tk = slot_token[slot];
                float wgt = slot_w[slot];            // pads have wgt=0 (memset path)
                if (wgt != 0.f) {
                    #pragma unroll
                    for (int q = 0; q < 2; q++)
                        atomicAdd(dst + (size_t)tk * D_OUT + wn * 32 + q * 16 + lrow,
                                  wgt * (acc[m][q][r] + bias_q[q]));
                }
            }
        }
    }
}

// ---------------- combine: out[t] = w0*routed[s0] + w1*routed[s1] ----------------
__global__ void combine_kernel(const float* __restrict__ routed, const int* __restrict__ inv_slot,
                               const float* __restrict__ topk_w, float* __restrict__ out) {
    int flat = blockIdx.x * 256 + threadIdx.x;       // float4 index
    int t = flat >> 6, c = (flat & 63) * 4;
    int   s0 = inv_slot[t*2], s1 = inv_slot[t*2+1];
    float w0 = topk_w[t*2],   w1 = topk_w[t*2+1];
    float4 r0 = *(const float4*)(routed + (size_t)s0 * D_OUT + c);
    float4 r1 = *(const float4*)(routed + (size_t)s1 * D_OUT + c);
    float4 o;
    o.x = w0*r0.x + w1*r1.x; o.y = w0*r0.y + w1*r1.y;
    o.z = w0*r0.z + w1*r1.z; o.w = w0*r0.w + w1*r1.w;
    *(float4*)(out + (size_t)t * D_OUT + c) = o;
}

extern "C" void kernel_launch(void* const* d_in, const int* in_sizes, int n_in,
                              void* d_out, int out_size, void* d_ws, size_t ws_size,
                              hipStream_t stream) {
    const float* x  = (const float*)d_in[0];
    const float* gW = (const float*)d_in[1];
    const float* gb = (const float*)d_in[2];
    const float* eW = (const float*)d_in[3];
    const float* eb = (const float*)d_in[4];
    float* out = (float*)d_out;
    char* ws = (char*)d_ws;

    // ws layout
    float* topk_w      = (float*)(ws + 0);                 // 256 KB
    int*   topk_e      = (int*)  (ws + 262144);            // 256 KB
    int*   counts      = (int*)  (ws + 524288);            // 8 ints
    int*   cursors     = (int*)  (ws + 524320);            // 8 ints  (contiguous w/ counts)
    int*   slot_token  = (int*)  (ws + 524416);            // 266240 B (S_PAD)
    float* slot_w      = (float*)(ws + 790656);            // 266240 B (S_PAD)
    int*   inv_slot    = (int*)  (ws + 1056896);           // 262144 B (S_TOT)
    unsigned short* WTb= (unsigned short*)(ws + 7610496);  // 3 MB bf16 W k-blocked
    unsigned short* xbf= (unsigned short*)(ws + 10756224); // 48 MB bf16 x
    float* routed      = (float*)(ws + 61087872);          // 68 MB routed outputs
    const size_t NEED_ROUTED = 61087872 + (size_t)S_PAD * D_OUT * 4;  // ~129 MB
    bool use_routed = (ws_size >= NEED_ROUTED);

    convw_kernel      <<<N_EXP * NKB, 256, 0, stream>>>(eW, WTb, counts);
    gate_fused_kernel <<<T_TOKENS / 32, 256, 0, stream>>>(x, gW, gb, xbf,
                                                          topk_w, topk_e, counts);
    scatter_kernel    <<<S_TOT / (256 * 4), 256, 0, stream>>>(topk_e, topk_w, counts, cursors,
                                                              slot_token, slot_w, inv_slot);
    if (use_routed) {
        moe_gemm_kernel<true><<<S_PAD / 128, 512, 0, stream>>>(xbf, WTb, eb, counts,
                                                               slot_token, slot_w, routed);
        combine_kernel<<<T_TOKENS * D_OUT / 4 / 256, 256, 0, stream>>>(routed, inv_slot,
                                                                       topk_w, out);
    } else {
        // fallback: pads must be (token=0, w=0) for the atomic path
        hipMemsetAsync(slot_token, 0, 532480, stream);
        hipMemsetAsync(out, 0, (size_t)out_size * sizeof(float), stream);
        moe_gemm_kernel<false><<<S_PAD / 128, 512, 0, stream>>>(xbf, WTb, eb, counts,
                                                                slot_token, slot_w, out);
    }
}

// Round 7
// 246.529 us; speedup vs baseline: 1.1917x; 1.0081x over previous
//
#include <hip/hip_runtime.h>
#include <hip/hip_bf16.h>
#include <stdint.h>

// Problem constants (fixed by reference setup_inputs)
#define T_TOKENS 32768     // 32*1024
#define D_IN     768
#define D_OUT    256
#define N_EXP    8
#define S_TOT    (T_TOKENS*2)   // 65536 routed slots
#define S_PAD    66560          // 65536 + 8*128 worst-case per-expert 128-padding
#define NKB      24             // K-blocks of 32 in d_in

typedef __attribute__((ext_vector_type(8))) short bf16x8;
typedef __attribute__((ext_vector_type(4))) float f32x4;

__device__ __forceinline__ unsigned short f2bf(float f) {
    unsigned u = __float_as_uint(f);
    return (unsigned short)((u + 0x7FFFu + ((u >> 16) & 1u)) >> 16);  // RNE
}
__device__ __forceinline__ unsigned pack_bf2(float a, float b) {
    return (unsigned)f2bf(a) | ((unsigned)f2bf(b) << 16);
}

// async global->LDS, 16B per lane. LDS dest must be wave-uniform base + lane*16.
__device__ __forceinline__ void async16(void* lds, const void* g) {
    __builtin_amdgcn_global_load_lds(
        (const __attribute__((address_space(1))) unsigned int*)g,
        (__attribute__((address_space(3))) unsigned int*)lds, 16, 0, 0);
}

// ---- W fp32 [e][k][n] -> bf16 k-blocked [e][kb][n][32kk]; zeroes counts+cursors ----
// Each (e,kb) tile is a contiguous 16 KB slab -> GEMM B reads are fully coalesced.
__global__ __launch_bounds__(256) void convw_kernel(
        const float* __restrict__ W, unsigned short* __restrict__ WTb,
        int* __restrict__ zero16) {
    if (blockIdx.x == 0 && threadIdx.x < 16) zero16[threadIdx.x] = 0;  // counts+cursors
    int eb_ = blockIdx.x;                            // e*NKB + kb, 0..191
    int n = threadIdx.x;
    const float* src = W + ((size_t)(eb_ / NKB) * D_IN + (eb_ % NKB) * 32) * 256 + n;
    unsigned pk[16];
    #pragma unroll
    for (int j = 0; j < 16; j++)                     // reads coalesced (n fastest)
        pk[j] = pack_bf2(src[(2*j) * 256], src[(2*j+1) * 256]);
    unsigned* dst = (unsigned*)(WTb + ((size_t)eb_ * 256 + n) * 32);  // 64 B/thread contig
    #pragma unroll
    for (int j = 0; j < 16; j++) dst[j] = pk[j];
}

// ---- FUSED gate, R7: barrier-free main loop, x direct from global ----
// Counter evidence (R4 gate): 1.7 TB/s (21% peak), VALUBusy 8% -> structure-bound
// (12 barriers/block + x round-trip through LDS), not BW-bound. New shape:
// thread (tt,qq) = token x k-eighth. Per kk-step the thread loads x[t][4qq+32kk..+3]
// as float4 straight from global (8 lanes x 16B = 128B contiguous per token),
// emits xbf from registers, and FMAs against gW held ENTIRELY in LDS (24 KB,
// loaded once -> ONE barrier per block). gW f4-index is XOR-swizzled
// (f ^ ((f>>3)&7), bijective, same formula both sides) so the 8 qq lanes hit 8
// distinct bank groups (conflict-free; broadcast across tt). 24 independent global
// loads/thread pipeline deeply; 24.6 KB LDS -> 6 blocks/CU (24 waves TLP).
__global__ __launch_bounds__(256) void gate_fused_kernel(
        const float* __restrict__ x, const float* __restrict__ gW,
        const float* __restrict__ gb, unsigned short* __restrict__ xbf,
        float* __restrict__ topk_w, int* __restrict__ topk_e,
        int* __restrict__ counts) {
    __shared__ float4 gws4[1536];                    // 24 KB: swizzled gW [768][8]
    __shared__ int h8[8];
    int tid = threadIdx.x;
    if (tid < 8) h8[tid] = 0;                        // covered by the single barrier
    #pragma unroll
    for (int i = 0; i < 6; ++i) {                    // cooperative gW load, coalesced
        int f = tid + i * 256;                       // f4 index over [768][8]
        gws4[f ^ ((f >> 3) & 7)] = *(const float4*)(gW + f * 4);
    }
    int t0 = blockIdx.x * 32;
    int tt = tid >> 3, qq = tid & 7;                 // token x k-eighth
    int t  = t0 + tt;
    const float*    xrow  = x   + (size_t)t * D_IN + qq * 4;
    unsigned short* xbrow = xbf + (size_t)t * D_IN + qq * 4;
    float acc[8] = {0,0,0,0,0,0,0,0};
    __syncthreads();                                 // gws4 + h8 visible; only barrier
    #pragma unroll 4
    for (int kk = 0; kk < 24; ++kk) {
        float4 v = *(const float4*)(xrow + kk * 32); // coalesced 128B/token
        uint2 p; p.x = pack_bf2(v.x, v.y); p.y = pack_bf2(v.z, v.w);
        *(uint2*)(xbrow + kk * 32) = p;              // fused bf16 emit (64B/token)
        float vv[4] = {v.x, v.y, v.z, v.w};
        #pragma unroll
        for (int j = 0; j < 4; ++j) {                // k = 4qq + 32kk + j
            int i0 = 8 * qq + 64 * kk + 2 * j;       // orig f4 idx of gW[k][0:4]
            float4 g0 = gws4[i0 ^ qq];               // (i>>3)&7 == qq for both halves
            float4 g1 = gws4[(i0 + 1) ^ qq];
            float xv = vv[j];
            acc[0] += xv * g0.x; acc[1] += xv * g0.y;
            acc[2] += xv * g0.z; acc[3] += xv * g0.w;
            acc[4] += xv * g1.x; acc[5] += xv * g1.y;
            acc[6] += xv * g1.z; acc[7] += xv * g1.w;
        }
    }
    #pragma unroll
    for (int e = 0; e < 8; ++e) {                    // fixed-order 8-lane reduce
        acc[e] += __shfl_xor(acc[e], 1);
        acc[e] += __shfl_xor(acc[e], 2);
        acc[e] += __shfl_xor(acc[e], 4);
    }
    if (qq == 0) {
        float mx = -1e30f;
        #pragma unroll
        for (int e = 0; e < 8; ++e) { acc[e] += gb[e]; mx = fmaxf(mx, acc[e]); }
        float w[8], s = 0.f;
        #pragma unroll
        for (int e = 0; e < 8; ++e) { w[e] = expf(acc[e] - mx); s += w[e]; }
        float inv = 1.0f / s;
        int e0 = 0; float b0 = -1.f;
        #pragma unroll
        for (int e = 0; e < 8; ++e) if (w[e] > b0) { b0 = w[e]; e0 = e; }
        int e1 = 0; float b1 = -1.f;
        #pragma unroll
        for (int e = 0; e < 8; ++e) if (e != e0 && w[e] > b1) { b1 = w[e]; e1 = e; }
        topk_w[t*2]   = b0 * inv;
        topk_w[t*2+1] = b1 * inv;
        topk_e[t*2]   = e0;
        topk_e[t*2+1] = e1;
        atomicAdd(&h8[e0], 1); atomicAdd(&h8[e1], 1);
    }
    __syncthreads();
    if (tid < 8) atomicAdd(&counts[tid], h8[tid]);
}

// ---- scatter (token,w) into expert buckets + inverse map; 128-aligned regions ----
// Block 0 additionally zeroes slot_w over the interior pad gaps (<=127 per expert).
__global__ void scatter_kernel(const int* __restrict__ topk_e, const float* __restrict__ topk_w,
                               const int* __restrict__ counts, int* __restrict__ cursors,
                               int* __restrict__ slot_token, float* __restrict__ slot_w,
                               int* __restrict__ inv_slot) {
    int offs[9]; offs[0] = 0;
    #pragma unroll
    for (int e = 0; e < 8; e++) offs[e+1] = offs[e] + ((counts[e] + 127) & ~127);
    if (blockIdx.x == 0) {                           // zero pad-gap weights
        #pragma unroll
        for (int e = 0; e < 8; e++) {
            int start = offs[e] + counts[e];
            for (int i = start + threadIdx.x; i < offs[e+1]; i += 256) slot_w[i] = 0.f;
        }
    }
    __shared__ int hcnt[8], hbase[8];
    if (threadIdx.x < 8) hcnt[threadIdx.x] = 0;
    __syncthreads();
    int idx[4], ee[4], lr[4];
    int base = blockIdx.x * 256 * 4 + threadIdx.x;
    #pragma unroll
    for (int j = 0; j < 4; j++) {
        idx[j] = base + j * 256;
        ee[j]  = topk_e[idx[j]];
        lr[j]  = atomicAdd(&hcnt[ee[j]], 1);
    }
    __syncthreads();
    if (threadIdx.x < 8) hbase[threadIdx.x] = atomicAdd(&cursors[threadIdx.x], hcnt[threadIdx.x]);
    __syncthreads();
    #pragma unroll
    for (int j = 0; j < 4; j++) {
        int slot = offs[ee[j]] + hbase[ee[j]] + lr[j];
        slot_token[slot] = idx[j] >> 1;
        slot_w[slot]     = topk_w[idx[j]];
        inv_slot[idx[j]] = slot;
    }
}

// ---- routed GEMM (unchanged from R6): 128x256 tile, 512 thr / 8 waves 1Mx8N,
// BK=32, B global->VGPR dist-1 double-buffer (loaded once per tile), A via
// 3-stage gload_lds pipeline, counted vmcnt(3), 24 KB LDS.
template<bool ROUTED>
__global__ __launch_bounds__(512, 4) void moe_gemm_kernel(
        const unsigned short* __restrict__ xbf, const unsigned short* __restrict__ WTb,
        const float* __restrict__ eb, const int* __restrict__ counts,
        const int* __restrict__ slot_token, const float* __restrict__ slot_w,
        float* __restrict__ dst) {
    __shared__ unsigned short A_lds[3][128 * 32];    // 3 x 8 KB = 24 KB total

    // bijective XCD-chunked swizzle: 520 = 8 * 65; consecutive lbid share B panel
    int lbid = (blockIdx.x & 7) * ((int)gridDim.x >> 3) + (blockIdx.x >> 3);

    int offs[9]; offs[0] = 0;
    #pragma unroll
    for (int e = 0; e < 8; e++) offs[e+1] = offs[e] + ((counts[e] + 127) & ~127);
    int row0 = lbid * 128;
    if (row0 >= offs[8]) return;                     // uniform exit (pad tiles)
    int expert = 0;
    #pragma unroll
    for (int e = 0; e < 8; e++) if (row0 >= offs[e]) expert = e;

    int tid  = threadIdx.x;
    int wave = tid >> 6, lane = tid & 63;
    int lrow = lane & 15, lquad = lane >> 4;
    int wn = wave;                                   // 1 (M) x 8 (N) wave grid

    // A: 512 16B-chunks (128 rows x 4) = 1 chunk/thread; gathered rows (row-major xbf)
    int ar = tid >> 2, ap = tid & 3;
    int alc = (ap - (ar >> 1)) & 3;                  // logical chunk at this phys slot
    int tok = slot_token[row0 + ar];
    tok = (tok < 0 || tok >= T_TOKENS) ? 0 : tok;    // pad slots hold garbage: clamp
    const unsigned short* asrc = xbf + (size_t)tok * D_IN + alc * 8;

    // B direct-load base: wave covers contiguous 1 KB per q (16 rows x 4 lquad chunks)
    const unsigned short* bptr = WTb + (size_t)expert * NKB * 8192
                                     + (wn * 32 + lrow) * 32 + lquad * 8;

    // A frag LDS offsets (shorts), constant across K; every wave reads all 128 rows
    int a_off[8];
    #pragma unroll
    for (int m = 0; m < 8; m++) {
        int r = m * 16 + lrow;
        a_off[m] = r * 32 + ((lquad + (r >> 1)) & 3) * 8;
    }

    f32x4 acc[8][2];
    #pragma unroll
    for (int m = 0; m < 8; m++)
        #pragma unroll
        for (int q = 0; q < 2; q++) acc[m][q] = (f32x4){0,0,0,0};

    bf16x8 bA[2], bB[2];
    auto bload = [&](int kb, bf16x8 (&b)[2]) {
        const unsigned short* bp = bptr + (size_t)kb * 8192;
        #pragma unroll
        for (int q = 0; q < 2; q++) b[q] = *(const bf16x8*)(bp + q * 512);
    };

    int rd = 0, wr = 2;                              // A stage read/write cursors
    auto kstep = [&](int s, bf16x8 (&bcur)[2], bf16x8 (&bnxt)[2]) {
        // FIFO at top of step s: [A(s), B(s)x2, A(s+1)] -> vmcnt(3) forces A(s).
        // Compiler inserts its own wait for bcur regs before the MFMAs.
        if (s == NKB - 1) asm volatile("s_waitcnt vmcnt(0)" ::: "memory");
        else              asm volatile("s_waitcnt vmcnt(3)" ::: "memory");
        asm volatile("s_barrier" ::: "memory");      // raw: no compiler vmcnt(0) drain
        if (s + 1 < NKB) bload(s + 1, bnxt);         // 2 VMEM (wave-private B regs)
        if (s + 2 < NKB)                             // 1 VMEM (A stage)
            async16(&A_lds[wr][tid * 8], asrc + (s + 2) * 32);
        #pragma unroll
        for (int g = 0; g < 2; ++g) {                // a-frags in 2 groups of 4
            bf16x8 a[4];
            #pragma unroll
            for (int m = 0; m < 4; ++m) a[m] = *(const bf16x8*)&A_lds[rd][a_off[g*4+m]];
            __builtin_amdgcn_s_setprio(1);
            #pragma unroll
            for (int q = 0; q < 2; ++q)
                #pragma unroll
                for (int m = 0; m < 4; ++m)
                    acc[g*4+m][q] = __builtin_amdgcn_mfma_f32_16x16x32_bf16(
                        a[m], bcur[q], acc[g*4+m][q], 0, 0, 0);
            __builtin_amdgcn_s_setprio(0);
        }
        rd = rd == 2 ? 0 : rd + 1;
        wr = wr == 2 ? 0 : wr + 1;
    };

    // prologue: A(0), A(1) oldest in vmcnt FIFO, then B(0)
    async16(&A_lds[0][tid * 8], asrc);
    async16(&A_lds[1][tid * 8], asrc + 32);
    __builtin_amdgcn_sched_barrier(0);               // pin A stages before bload
    bload(0, bA);
    for (int s = 0; s < NKB; s += 2) {               // NKB even
        kstep(s, bA, bB);
        kstep(s + 1, bB, bA);
    }

    // epilogue: D mapping col=lane&15, row=quad*4+reg
    float bias_q[2];
    #pragma unroll
    for (int q = 0; q < 2; q++)
        bias_q[q] = eb[expert * D_OUT + wn * 32 + q * 16 + lrow];
    #pragma unroll
    for (int m = 0; m < 8; m++) {
        #pragma unroll
        for (int r = 0; r < 4; r++) {
            int slot = row0 + m * 16 + lquad * 4 + r;
            if constexpr (ROUTED) {
                float* drow = dst + (size_t)slot * D_OUT + wn * 32;
                #pragma unroll
                for (int q = 0; q < 2; q++)
                    drow[q * 16 + lrow] = acc[m][q][r] + bias_q[q];
            } else {
                int tk = slot_token[slot];
                float wgt = slot_w[slot];            // pads have wgt=0 (memset path)
                if (wgt != 0.f) {
                    #pragma unroll
                    for (int q = 0; q < 2; q++)
                        atomicAdd(dst + (size_t)tk * D_OUT + wn * 32 + q * 16 + lrow,
                                  wgt * (acc[m][q][r] + bias_q[q]));
                }
            }
        }
    }
}

// ---------------- combine: out[t] = w0*routed[s0] + w1*routed[s1] ----------------
__global__ void combine_kernel(const float* __restrict__ routed, const int* __restrict__ inv_slot,
                               const float* __restrict__ topk_w, float* __restrict__ out) {
    int flat = blockIdx.x * 256 + threadIdx.x;       // float4 index
    int t = flat >> 6, c = (flat & 63) * 4;
    int   s0 = inv_slot[t*2], s1 = inv_slot[t*2+1];
    float w0 = topk_w[t*2],   w1 = topk_w[t*2+1];
    float4 r0 = *(const float4*)(routed + (size_t)s0 * D_OUT + c);
    float4 r1 = *(const float4*)(routed + (size_t)s1 * D_OUT + c);
    float4 o;
    o.x = w0*r0.x + w1*r1.x; o.y = w0*r0.y + w1*r1.y;
    o.z = w0*r0.z + w1*r1.z; o.w = w0*r0.w + w1*r1.w;
    *(float4*)(out + (size_t)t * D_OUT + c) = o;
}

extern "C" void kernel_launch(void* const* d_in, const int* in_sizes, int n_in,
                              void* d_out, int out_size, void* d_ws, size_t ws_size,
                              hipStream_t stream) {
    const float* x  = (const float*)d_in[0];
    const float* gW = (const float*)d_in[1];
    const float* gb = (const float*)d_in[2];
    const float* eW = (const float*)d_in[3];
    const float* eb = (const float*)d_in[4];
    float* out = (float*)d_out;
    char* ws = (char*)d_ws;

    // ws layout
    float* topk_w      = (float*)(ws + 0);                 // 256 KB
    int*   topk_e      = (int*)  (ws + 262144);            // 256 KB
    int*   counts      = (int*)  (ws + 524288);            // 8 ints
    int*   cursors     = (int*)  (ws + 524320);            // 8 ints  (contiguous w/ counts)
    int*   slot_token  = (int*)  (ws + 524416);            // 266240 B (S_PAD)
    float* slot_w      = (float*)(ws + 790656);            // 266240 B (S_PAD)
    int*   inv_slot    = (int*)  (ws + 1056896);           // 262144 B (S_TOT)
    unsigned short* WTb= (unsigned short*)(ws + 7610496);  // 3 MB bf16 W k-blocked
    unsigned short* xbf= (unsigned short*)(ws + 10756224); // 48 MB bf16 x
    float* routed      = (float*)(ws + 61087872);          // 68 MB routed outputs
    const size_t NEED_ROUTED = 61087872 + (size_t)S_PAD * D_OUT * 4;  // ~129 MB
    bool use_routed = (ws_size >= NEED_ROUTED);

    convw_kernel      <<<N_EXP * NKB, 256, 0, stream>>>(eW, WTb, counts);
    gate_fused_kernel <<<T_TOKENS / 32, 256, 0, stream>>>(x, gW, gb, xbf,
                                                          topk_w, topk_e, counts);
    scatter_kernel    <<<S_TOT / (256 * 4), 256, 0, stream>>>(topk_e, topk_w, counts, cursors,
                                                              slot_token, slot_w, inv_slot);
    if (use_routed) {
        moe_gemm_kernel<true><<<S_PAD / 128, 512, 0, stream>>>(xbf, WTb, eb, counts,
                                                               slot_token, slot_w, routed);
        combine_kernel<<<T_TOKENS * D_OUT / 4 / 256, 256, 0, stream>>>(routed, inv_slot,
                                                                       topk_w, out);
    } else {
        // fallback: pads must be (token=0, w=0) for the atomic path
        hipMemsetAsync(slot_token, 0, 532480, stream);
        hipMemsetAsync(out, 0, (size_t)out_size * sizeof(float), stream);
        moe_gemm_kernel<false><<<S_PAD / 128, 512, 0, stream>>>(xbf, WTb, eb, counts,
                                                                slot_token, slot_w, out);
    }
}

// Round 8
// 244.412 us; speedup vs baseline: 1.2020x; 1.0087x over previous
//
#include <hip/hip_runtime.h>
#include <hip/hip_bf16.h>
#include <stdint.h>

// Problem constants (fixed by reference setup_inputs)
#define T_TOKENS 32768     // 32*1024
#define D_IN     768
#define D_OUT    256
#define N_EXP    8
#define S_TOT    (T_TOKENS*2)   // 65536 routed slots
#define S_PAD    66560          // 65536 + 8*128 worst-case per-expert 128-padding
#define NKB      24             // K-blocks of 32 in d_in
#define NT2      12             // double K-steps (BK=64)

typedef __attribute__((ext_vector_type(8))) short bf16x8;
typedef __attribute__((ext_vector_type(4))) float f32x4;

__device__ __forceinline__ unsigned short f2bf(float f) {
    unsigned u = __float_as_uint(f);
    return (unsigned short)((u + 0x7FFFu + ((u >> 16) & 1u)) >> 16);  // RNE
}
__device__ __forceinline__ unsigned pack_bf2(float a, float b) {
    return (unsigned)f2bf(a) | ((unsigned)f2bf(b) << 16);
}

// async global->LDS, 16B per lane. LDS dest must be wave-uniform base + lane*16.
__device__ __forceinline__ void async16(void* lds, const void* g) {
    __builtin_amdgcn_global_load_lds(
        (const __attribute__((address_space(1))) unsigned int*)g,
        (__attribute__((address_space(3))) unsigned int*)lds, 16, 0, 0);
}

// ---- W fp32 [e][k][n] -> bf16 k-blocked [e][kb][n][32kk]; zeroes counts+cursors ----
// Each (e,kb) tile is a contiguous 16 KB slab -> GEMM B reads are fully coalesced.
__global__ __launch_bounds__(256) void convw_kernel(
        const float* __restrict__ W, unsigned short* __restrict__ WTb,
        int* __restrict__ zero16) {
    if (blockIdx.x == 0 && threadIdx.x < 16) zero16[threadIdx.x] = 0;  // counts+cursors
    int eb_ = blockIdx.x;                            // e*NKB + kb, 0..191
    int n = threadIdx.x;
    const float* src = W + ((size_t)(eb_ / NKB) * D_IN + (eb_ % NKB) * 32) * 256 + n;
    unsigned pk[16];
    #pragma unroll
    for (int j = 0; j < 16; j++)                     // reads coalesced (n fastest)
        pk[j] = pack_bf2(src[(2*j) * 256], src[(2*j+1) * 256]);
    unsigned* dst = (unsigned*)(WTb + ((size_t)eb_ * 256 + n) * 32);  // 64 B/thread contig
    #pragma unroll
    for (int j = 0; j < 16; j++) dst[j] = pk[j];
}

// ---- FUSED gate (unchanged from R7): barrier-free main loop, x direct from global,
// gW entirely in LDS (XOR-swizzled, conflict-free broadcast reads), fused xbf emit.
__global__ __launch_bounds__(256) void gate_fused_kernel(
        const float* __restrict__ x, const float* __restrict__ gW,
        const float* __restrict__ gb, unsigned short* __restrict__ xbf,
        float* __restrict__ topk_w, int* __restrict__ topk_e,
        int* __restrict__ counts) {
    __shared__ float4 gws4[1536];                    // 24 KB: swizzled gW [768][8]
    __shared__ int h8[8];
    int tid = threadIdx.x;
    if (tid < 8) h8[tid] = 0;                        // covered by the single barrier
    #pragma unroll
    for (int i = 0; i < 6; ++i) {                    // cooperative gW load, coalesced
        int f = tid + i * 256;                       // f4 index over [768][8]
        gws4[f ^ ((f >> 3) & 7)] = *(const float4*)(gW + f * 4);
    }
    int t0 = blockIdx.x * 32;
    int tt = tid >> 3, qq = tid & 7;                 // token x k-eighth
    int t  = t0 + tt;
    const float*    xrow  = x   + (size_t)t * D_IN + qq * 4;
    unsigned short* xbrow = xbf + (size_t)t * D_IN + qq * 4;
    float acc[8] = {0,0,0,0,0,0,0,0};
    __syncthreads();                                 // gws4 + h8 visible; only barrier
    #pragma unroll 4
    for (int kk = 0; kk < 24; ++kk) {
        float4 v = *(const float4*)(xrow + kk * 32); // coalesced 128B/token
        uint2 p; p.x = pack_bf2(v.x, v.y); p.y = pack_bf2(v.z, v.w);
        *(uint2*)(xbrow + kk * 32) = p;              // fused bf16 emit (64B/token)
        float vv[4] = {v.x, v.y, v.z, v.w};
        #pragma unroll
        for (int j = 0; j < 4; ++j) {                // k = 4qq + 32kk + j
            int i0 = 8 * qq + 64 * kk + 2 * j;       // orig f4 idx of gW[k][0:4]
            float4 g0 = gws4[i0 ^ qq];               // (i>>3)&7 == qq for both halves
            float4 g1 = gws4[(i0 + 1) ^ qq];
            float xv = vv[j];
            acc[0] += xv * g0.x; acc[1] += xv * g0.y;
            acc[2] += xv * g0.z; acc[3] += xv * g0.w;
            acc[4] += xv * g1.x; acc[5] += xv * g1.y;
            acc[6] += xv * g1.z; acc[7] += xv * g1.w;
        }
    }
    #pragma unroll
    for (int e = 0; e < 8; ++e) {                    // fixed-order 8-lane reduce
        acc[e] += __shfl_xor(acc[e], 1);
        acc[e] += __shfl_xor(acc[e], 2);
        acc[e] += __shfl_xor(acc[e], 4);
    }
    if (qq == 0) {
        float mx = -1e30f;
        #pragma unroll
        for (int e = 0; e < 8; ++e) { acc[e] += gb[e]; mx = fmaxf(mx, acc[e]); }
        float w[8], s = 0.f;
        #pragma unroll
        for (int e = 0; e < 8; ++e) { w[e] = expf(acc[e] - mx); s += w[e]; }
        float inv = 1.0f / s;
        int e0 = 0; float b0 = -1.f;
        #pragma unroll
        for (int e = 0; e < 8; ++e) if (w[e] > b0) { b0 = w[e]; e0 = e; }
        int e1 = 0; float b1 = -1.f;
        #pragma unroll
        for (int e = 0; e < 8; ++e) if (e != e0 && w[e] > b1) { b1 = w[e]; e1 = e; }
        topk_w[t*2]   = b0 * inv;
        topk_w[t*2+1] = b1 * inv;
        topk_e[t*2]   = e0;
        topk_e[t*2+1] = e1;
        atomicAdd(&h8[e0], 1); atomicAdd(&h8[e1], 1);
    }
    __syncthreads();
    if (tid < 8) atomicAdd(&counts[tid], h8[tid]);
}

// ---- scatter (token,w) into expert buckets + inverse map; 128-aligned regions ----
// Block 0 additionally zeroes slot_w over the interior pad gaps (<=127 per expert).
__global__ void scatter_kernel(const int* __restrict__ topk_e, const float* __restrict__ topk_w,
                               const int* __restrict__ counts, int* __restrict__ cursors,
                               int* __restrict__ slot_token, float* __restrict__ slot_w,
                               int* __restrict__ inv_slot) {
    int offs[9]; offs[0] = 0;
    #pragma unroll
    for (int e = 0; e < 8; e++) offs[e+1] = offs[e] + ((counts[e] + 127) & ~127);
    if (blockIdx.x == 0) {                           // zero pad-gap weights
        #pragma unroll
        for (int e = 0; e < 8; e++) {
            int start = offs[e] + counts[e];
            for (int i = start + threadIdx.x; i < offs[e+1]; i += 256) slot_w[i] = 0.f;
        }
    }
    __shared__ int hcnt[8], hbase[8];
    if (threadIdx.x < 8) hcnt[threadIdx.x] = 0;
    __syncthreads();
    int idx[4], ee[4], lr[4];
    int base = blockIdx.x * 256 * 4 + threadIdx.x;
    #pragma unroll
    for (int j = 0; j < 4; j++) {
        idx[j] = base + j * 256;
        ee[j]  = topk_e[idx[j]];
        lr[j]  = atomicAdd(&hcnt[ee[j]], 1);
    }
    __syncthreads();
    if (threadIdx.x < 8) hbase[threadIdx.x] = atomicAdd(&cursors[threadIdx.x], hcnt[threadIdx.x]);
    __syncthreads();
    #pragma unroll
    for (int j = 0; j < 4; j++) {
        int slot = offs[ee[j]] + hbase[ee[j]] + lr[j];
        slot_token[slot] = idx[j] >> 1;
        slot_w[slot]     = topk_w[idx[j]];
        inv_slot[idx[j]] = slot;
    }
}

// ---- routed GEMM, R8: BK=64 (two 32-k blocks per barrier). 128x256 tile, 512 thr
// / 8 waves 1Mx8N. Rationale: barrier rhythm was the residual — 24 vmcnt+barrier
// pairs covering only 16 MFMA/wave each; BK=64 halves them (12 pairs, 32 MFMA/wave
// each). A-stage = 16 KB (2 halves, 2 async16/thread), 3 stages = 48 KB LDS (still
// 2 blocks/CU). B stays global->VGPR: bEv loop-carried dist-1, bOdd intra-step.
// Counted-vmcnt (6 VMEM/step: bOdd 2 + stage 2 + bEv 2), safe under ANY intra-step
// reorder (in-order vmcnt retirement; worst-case >=6 loads issued after stage(t)):
// vmcnt(6) steady, vmcnt(4) at t=0 (prologue: only 4 loads after stage 0) and at
// the final step (no stage issued in the penultimate step).
template<bool ROUTED>
__global__ __launch_bounds__(512, 4) void moe_gemm_kernel(
        const unsigned short* __restrict__ xbf, const unsigned short* __restrict__ WTb,
        const float* __restrict__ eb, const int* __restrict__ counts,
        const int* __restrict__ slot_token, const float* __restrict__ slot_w,
        float* __restrict__ dst) {
    __shared__ unsigned short A_lds[3][2][128 * 32];  // 3 x 16 KB = 48 KB

    // bijective XCD-chunked swizzle: 520 = 8 * 65; consecutive lbid share B panel
    int lbid = (blockIdx.x & 7) * ((int)gridDim.x >> 3) + (blockIdx.x >> 3);

    int offs[9]; offs[0] = 0;
    #pragma unroll
    for (int e = 0; e < 8; e++) offs[e+1] = offs[e] + ((counts[e] + 127) & ~127);
    int row0 = lbid * 128;
    if (row0 >= offs[8]) return;                     // uniform exit (pad tiles)
    int expert = 0;
    #pragma unroll
    for (int e = 0; e < 8; e++) if (row0 >= offs[e]) expert = e;

    int tid  = threadIdx.x;
    int wave = tid >> 6, lane = tid & 63;
    int lrow = lane & 15, lquad = lane >> 4;
    int wn = wave;                                   // 1 (M) x 8 (N) wave grid

    // A: per 32-k block, 512 16B-chunks (128 rows x 4) = 1 chunk/thread
    int ar = tid >> 2, ap = tid & 3;
    int alc = (ap - (ar >> 1)) & 3;                  // logical chunk at this phys slot
    int tok = slot_token[row0 + ar];
    tok = (tok < 0 || tok >= T_TOKENS) ? 0 : tok;    // pad slots hold garbage: clamp
    const unsigned short* asrc = xbf + (size_t)tok * D_IN + alc * 8;

    // B direct-load base: wave covers contiguous 1 KB per q (16 rows x 4 lquad chunks)
    const unsigned short* bptr = WTb + (size_t)expert * NKB * 8192
                                     + (wn * 32 + lrow) * 32 + lquad * 8;

    // A frag LDS offsets (shorts) within one 8 KB k-block; constant across K
    int a_off[8];
    #pragma unroll
    for (int m = 0; m < 8; m++) {
        int r = m * 16 + lrow;
        a_off[m] = r * 32 + ((lquad + (r >> 1)) & 3) * 8;
    }

    f32x4 acc[8][2];
    #pragma unroll
    for (int m = 0; m < 8; m++)
        #pragma unroll
        for (int q = 0; q < 2; q++) acc[m][q] = (f32x4){0,0,0,0};

    auto bload = [&](int kb, bf16x8 (&b)[2]) {
        const unsigned short* bp = bptr + (size_t)kb * 8192;
        #pragma unroll
        for (int q = 0; q < 2; q++) b[q] = *(const bf16x8*)(bp + q * 512);
    };
    auto stageA = [&](int st, int t2) {              // 2 async16: k-blocks 2t2, 2t2+1
        async16(&A_lds[st][0][tid * 8], asrc + (2 * t2) * 32);
        async16(&A_lds[st][1][tid * 8], asrc + (2 * t2 + 1) * 32);
    };
    auto half = [&](const unsigned short* base, bf16x8 (&b)[2]) {
        #pragma unroll
        for (int g = 0; g < 2; ++g) {                // a-frags in 2 groups of 4
            bf16x8 a[4];
            #pragma unroll
            for (int m = 0; m < 4; ++m) a[m] = *(const bf16x8*)&base[a_off[g*4+m]];
            __builtin_amdgcn_s_setprio(1);
            #pragma unroll
            for (int q = 0; q < 2; ++q)
                #pragma unroll
                for (int m = 0; m < 4; ++m)
                    acc[g*4+m][q] = __builtin_amdgcn_mfma_f32_16x16x32_bf16(
                        a[m], b[q], acc[g*4+m][q], 0, 0, 0);
            __builtin_amdgcn_s_setprio(0);
        }
    };

    // prologue: A stages oldest in vmcnt FIFO, then B(0)
    stageA(0, 0);
    stageA(1, 1);
    __builtin_amdgcn_sched_barrier(0);               // pin A stages before bload
    bf16x8 bEv[2];
    bload(0, bEv);

    for (int t = 0; t < NT2; ++t) {
        if (t == 0 || t == NT2 - 1) asm volatile("s_waitcnt vmcnt(4)" ::: "memory");
        else                        asm volatile("s_waitcnt vmcnt(6)" ::: "memory");
        asm volatile("s_barrier" ::: "memory");      // raw: no compiler vmcnt(0) drain
        bf16x8 bOdd[2];
        bload(2 * t + 1, bOdd);                      // 2 VMEM
        if (t + 2 < NT2) stageA((t + 2) % 3, t + 2); // 2 VMEM (overwrites stage t-1)
        half(&A_lds[t % 3][0][0], bEv);              // k-block 2t
        bf16x8 bEvN[2];
        if (t + 1 < NT2) bload(2 * t + 2, bEvN);     // 2 VMEM (next even block)
        half(&A_lds[t % 3][1][0], bOdd);             // k-block 2t+1
        if (t + 1 < NT2) { bEv[0] = bEvN[0]; bEv[1] = bEvN[1]; }
    }

    // epilogue: D mapping col=lane&15, row=quad*4+reg
    float bias_q[2];
    #pragma unroll
    for (int q = 0; q < 2; q++)
        bias_q[q] = eb[expert * D_OUT + wn * 32 + q * 16 + lrow];
    #pragma unroll
    for (int m = 0; m < 8; m++) {
        #pragma unroll
        for (int r = 0; r < 4; r++) {
            int slot = row0 + m * 16 + lquad * 4 + r;
            if constexpr (ROUTED) {
                float* drow = dst + (size_t)slot * D_OUT + wn * 32;
                #pragma unroll
                for (int q = 0; q < 2; q++)
                    drow[q * 16 + lrow] = acc[m][q][r] + bias_q[q];
            } else {
                int tk = slot_token[slot];
                float wgt = slot_w[slot];            // pads have wgt=0 (memset path)
                if (wgt != 0.f) {
                    #pragma unroll
                    for (int q = 0; q < 2; q++)
                        atomicAdd(dst + (size_t)tk * D_OUT + wn * 32 + q * 16 + lrow,
                                  wgt * (acc[m][q][r] + bias_q[q]));
                }
            }
        }
    }
}

// ---------------- combine: out[t] = w0*routed[s0] + w1*routed[s1] ----------------
__global__ void combine_kernel(const float* __restrict__ routed, const int* __restrict__ inv_slot,
                               const float* __restrict__ topk_w, float* __restrict__ out) {
    int flat = blockIdx.x * 256 + threadIdx.x;       // float4 index
    int t = flat >> 6, c = (flat & 63) * 4;
    int   s0 = inv_slot[t*2], s1 = inv_slot[t*2+1];
    float w0 = topk_w[t*2],   w1 = topk_w[t*2+1];
    float4 r0 = *(const float4*)(routed + (size_t)s0 * D_OUT + c);
    float4 r1 = *(const float4*)(routed + (size_t)s1 * D_OUT + c);
    float4 o;
    o.x = w0*r0.x + w1*r1.x; o.y = w0*r0.y + w1*r1.y;
    o.z = w0*r0.z + w1*r1.z; o.w = w0*r0.w + w1*r1.w;
    *(float4*)(out + (size_t)t * D_OUT + c) = o;
}

extern "C" void kernel_launch(void* const* d_in, const int* in_sizes, int n_in,
                              void* d_out, int out_size, void* d_ws, size_t ws_size,
                              hipStream_t stream) {
    const float* x  = (const float*)d_in[0];
    const float* gW = (const float*)d_in[1];
    const float* gb = (const float*)d_in[2];
    const float* eW = (const float*)d_in[3];
    const float* eb = (const float*)d_in[4];
    float* out = (float*)d_out;
    char* ws = (char*)d_ws;

    // ws layout
    float* topk_w      = (float*)(ws + 0);                 // 256 KB
    int*   topk_e      = (int*)  (ws + 262144);            // 256 KB
    int*   counts      = (int*)  (ws + 524288);            // 8 ints
    int*   cursors     = (int*)  (ws + 524320);            // 8 ints  (contiguous w/ counts)
    int*   slot_token  = (int*)  (ws + 524416);            // 266240 B (S_PAD)
    float* slot_w      = (float*)(ws + 790656);            // 266240 B (S_PAD)
    int*   inv_slot    = (int*)  (ws + 1056896);           // 262144 B (S_TOT)
    unsigned short* WTb= (unsigned short*)(ws + 7610496);  // 3 MB bf16 W k-blocked
    unsigned short* xbf= (unsigned short*)(ws + 10756224); // 48 MB bf16 x
    float* routed      = (float*)(ws + 61087872);          // 68 MB routed outputs
    const size_t NEED_ROUTED = 61087872 + (size_t)S_PAD * D_OUT * 4;  // ~129 MB
    bool use_routed = (ws_size >= NEED_ROUTED);

    convw_kernel      <<<N_EXP * NKB, 256, 0, stream>>>(eW, WTb, counts);
    gate_fused_kernel <<<T_TOKENS / 32, 256, 0, stream>>>(x, gW, gb, xbf,
                                                          topk_w, topk_e, counts);
    scatter_kernel    <<<S_TOT / (256 * 4), 256, 0, stream>>>(topk_e, topk_w, counts, cursors,
                                                              slot_token, slot_w, inv_slot);
    if (use_routed) {
        moe_gemm_kernel<true><<<S_PAD / 128, 512, 0, stream>>>(xbf, WTb, eb, counts,
                                                               slot_token, slot_w, routed);
        combine_kernel<<<T_TOKENS * D_OUT / 4 / 256, 256, 0, stream>>>(routed, inv_slot,
                                                                       topk_w, out);
    } else {
        // fallback: pads must be (token=0, w=0) for the atomic path
        hipMemsetAsync(slot_token, 0, 532480, stream);
        hipMemsetAsync(out, 0, (size_t)out_size * sizeof(float), stream);
        moe_gemm_kernel<false><<<S_PAD / 128, 512, 0, stream>>>(xbf, WTb, eb, counts,
                                                                slot_token, slot_w, out);
    }
}